// Round 15
// baseline (809.611 us; speedup 1.0000x reference)
//
#include <hip/hip_runtime.h>

#define N_NODES 50000
#define N_EDGES 800000
#define N_GRAPHS 2048
#define IN_DIM 128
#define HID 256
#define N_LAYERS 4
#define BN_EPS 1e-5f
#define NBIN 128
#define NRF 3125   // N_NODES/16 row-frags (exact)

typedef unsigned short ushort_t;
typedef __bf16 bf16x8 __attribute__((ext_vector_type(8)));
typedef float f32x4 __attribute__((ext_vector_type(4)));
typedef unsigned int u32x2 __attribute__((ext_vector_type(2)));

// ---- fp32 -> bf16 (round-to-nearest-even) helpers ----
__device__ __forceinline__ ushort_t f2bf_rn(float x) {
    unsigned int u = __float_as_uint(x);
    u += 0x7FFFu + ((u >> 16) & 1u);
    return (ushort_t)(u >> 16);
}
__device__ __forceinline__ float bf2f(ushort_t h) {
    return __uint_as_float(((unsigned int)h) << 16);
}

// ---------------- degree count ----------------
__global__ void k_deg(const int* __restrict__ dst, int* __restrict__ degi, int E) {
    int e = blockIdx.x * blockDim.x + threadIdx.x;
    if (e < E) atomicAdd(&degi[dst[e]], 1);
}

__global__ void k_nodenorm(const int* __restrict__ degi, float* __restrict__ dinv,
                           float* __restrict__ selfn, int N) {
    int n = blockIdx.x * blockDim.x + threadIdx.x;
    if (n < N) {
        float d = 1.0f + (float)degi[n];
        dinv[n] = 1.0f / sqrtf(d);
        selfn[n] = 1.0f / d;
    }
}

// ---------------- degree histogram (hierarchical) ----------------
__global__ __launch_bounds__(256) void k_hist(const int* __restrict__ degi,
                                              int* __restrict__ bins, int N) {
    __shared__ int lbin[NBIN];
    int t = threadIdx.x;
    if (t < NBIN) lbin[t] = 0;
    __syncthreads();
    int n = blockIdx.x * 256 + t;
    if (n < N) atomicAdd(&lbin[min(degi[n], NBIN - 1)], 1);
    __syncthreads();
    if (t < NBIN && lbin[t] > 0) atomicAdd(&bins[t], lbin[t]);
}

// ---------------- bin prefix (tiny serial, 128 iters) ----------------
__global__ void k_binscan(const int* __restrict__ bins, int* __restrict__ binstart,
                          int* __restrict__ bincur, int* __restrict__ edgebase) {
    if (threadIdx.x == 0) {
        int run = 0, erun = 0;
        for (int d = 0; d < NBIN; ++d) {
            binstart[d] = run;
            bincur[d] = run;
            edgebase[d] = erun;
            run += bins[d];
            erun += bins[d] * d;
        }
    }
}

// ---------------- parallel slot assignment, hierarchical; emits per-slot meta ----------------
__global__ __launch_bounds__(256) void k_assign(const int* __restrict__ degi,
                                                const int* __restrict__ binstart,
                                                const int* __restrict__ edgebase,
                                                const int* __restrict__ bins,
                                                int* __restrict__ bincur,
                                                int* __restrict__ perm, int* __restrict__ invperm,
                                                int2* __restrict__ meta, int* __restrict__ cursor,
                                                int N) {
    __shared__ int lbin[NBIN];
    __shared__ int lbase[NBIN];
    int t = threadIdx.x;
    if (t < NBIN) lbin[t] = 0;
    __syncthreads();
    int n = blockIdx.x * 256 + t;
    int d = 0, lrank = 0;
    if (n < N) {
        d = min(degi[n], NBIN - 1);
        lrank = atomicAdd(&lbin[d], 1);
    }
    __syncthreads();
    if (t < NBIN && lbin[t] > 0) lbase[t] = atomicAdd(&bincur[t], lbin[t]);
    __syncthreads();
    if (n < N) {
        int slot = lbase[d] + lrank;
        perm[slot] = n;
        invperm[n] = slot;
        int2 m;
        m.x = edgebase[d] + (slot - binstart[d]);
        m.y = bins[d] | (d << 20);
        meta[slot] = m;
        cursor[slot] = 0;
    }
}

// ---------------- CSR fill into bin-interleaved layout ----------------
__global__ void k_fill(const int* __restrict__ src, const int* __restrict__ dst,
                       const float* __restrict__ dinv, const int* __restrict__ invperm,
                       const int2* __restrict__ meta, int* __restrict__ cursor,
                       int2* __restrict__ edata, int E) {
    int e = blockIdx.x * blockDim.x + threadIdx.x;
    if (e >= E) return;
    int s = src[e], d = dst[e];
    int slot = invperm[d];
    int2 m = meta[slot];
    int j = atomicAdd(&cursor[slot], 1);
    int pos = m.x + j * (m.y & 0xFFFFF);
    int2 v;
    v.x = s;
    v.y = __float_as_int(dinv[s] * dinv[d]);
    edata[pos] = v;
}

// ---- fragment-order addressing: element (n,k) of a K-wide matrix ----
// frag = (rf = n>>4, ks = k>>5); lane = ((k>>3)&3)*16 + (n&15); j = k&7
// addr = ((rf*KS + ks)*64 + lane)*8 + j      (KS = K/32)

// ---------------- split x -> bf16 hi/lo in FRAG ORDER (K=128, KS=4) ----------------
__global__ __launch_bounds__(256) void k_splitx(const float* __restrict__ x,
                                                ushort_t* __restrict__ Ah,
                                                ushort_t* __restrict__ Al, int total4) {
    int i = blockIdx.x * blockDim.x + threadIdx.x;
    if (i >= total4) return;
    float4 v = ((const float4*)x)[i];
    ushort4 h, l;
    h.x = f2bf_rn(v.x); l.x = f2bf_rn(v.x - bf2f(h.x));
    h.y = f2bf_rn(v.y); l.y = f2bf_rn(v.y - bf2f(h.y));
    h.z = f2bf_rn(v.z); l.z = f2bf_rn(v.z - bf2f(h.z));
    h.w = f2bf_rn(v.w); l.w = f2bf_rn(v.w - bf2f(h.w));
    int n = i >> 5;
    int k0 = (i & 31) * 4;
    int rf = n >> 4, mm = n & 15;
    int ks = k0 >> 5, q = (k0 >> 3) & 3, j0 = k0 & 7;
    size_t addr = ((size_t)(rf * 4 + ks) * 64 + q * 16 + mm) * 8 + j0;
    *(ushort4*)(Ah + addr) = h;
    *(ushort4*)(Al + addr) = l;
}

// ---------------- split + transpose weights into FRAG ORDER ----------------
__global__ void k_splitw(const float* __restrict__ W0, const float* __restrict__ Ws,
                         ushort_t* __restrict__ Wh, ushort_t* __restrict__ Wl) {
    int i = blockIdx.x * blockDim.x + threadIdx.x;
    const int total = 128 * 256 + 3 * 256 * 256;
    if (i >= total) return;
    float v;
    int n, k, KS;
    size_t base;
    if (i < 32768) {
        n = i >> 7; k = i & 127;
        v = W0[k * 256 + n];
        KS = 4; base = 0;
    } else {
        int t = i - 32768;
        int l = t >> 16;
        int r = t & 65535;
        n = r >> 8; k = r & 255;
        v = Ws[l * 65536 + k * 256 + n];
        KS = 8; base = 32768 + (size_t)l * 65536;
    }
    ushort_t h = f2bf_rn(v);
    int nf = n >> 4, mm = n & 15;
    int ks = k >> 5, q = (k >> 3) & 3, j = k & 7;
    size_t addr = base + ((size_t)(nf * KS + ks) * 64 + q * 16 + mm) * 8 + j;
    Wh[addr] = h;
    Wl[addr] = f2bf_rn(v - bf2f(h));
}

// ---------------- LDS-free MFMA GEMM from fragment-order operands ----------------
// Block 256 thr = 4 waves (2x2); block tile 128 rows x 128 cols; no LDS, no barriers.
// A/W read as wave-coalesced 1KB bf16x8 frag loads straight from L2/L3.
// Output H in CHUNK-MAJOR [16][N][16].
__global__ __launch_bounds__(256) void k_gemm(const ushort_t* __restrict__ Ah,
                                              const ushort_t* __restrict__ Al,
                                              const ushort_t* __restrict__ Wh,
                                              const ushort_t* __restrict__ Wl,
                                              float* __restrict__ H, int KS) {
    int lane = threadIdx.x & 63;
    int w = threadIdx.x >> 6;
    int wrow = w & 1, wcol = w >> 1;
    int rfb = blockIdx.x * 8 + wrow * 4;   // row-frag base (NRF total)
    int nfb = blockIdx.y * 8 + wcol * 4;   // col-frag base (16 total)

    f32x4 acc[4][4] = {};

    #pragma unroll 2
    for (int ks = 0; ks < KS; ++ks) {
        bf16x8 ahf[4], alf[4], whf[4], wlf[4];
        #pragma unroll
        for (int r = 0; r < 4; ++r) {
            int rf = min(rfb + r, NRF - 1);
            size_t off = ((size_t)(rf * KS + ks) * 64 + lane) * 8;
            ahf[r] = *(const bf16x8*)(Ah + off);
            alf[r] = *(const bf16x8*)(Al + off);
        }
        #pragma unroll
        for (int c = 0; c < 4; ++c) {
            size_t off = ((size_t)((nfb + c) * KS + ks) * 64 + lane) * 8;
            whf[c] = *(const bf16x8*)(Wh + off);
            wlf[c] = *(const bf16x8*)(Wl + off);
        }
        #pragma unroll
        for (int r = 0; r < 4; ++r)
            #pragma unroll
            for (int c = 0; c < 4; ++c) {
                acc[r][c] = __builtin_amdgcn_mfma_f32_16x16x32_bf16(ahf[r], whf[c], acc[r][c], 0, 0, 0);
                acc[r][c] = __builtin_amdgcn_mfma_f32_16x16x32_bf16(ahf[r], wlf[c], acc[r][c], 0, 0, 0);
                acc[r][c] = __builtin_amdgcn_mfma_f32_16x16x32_bf16(alf[r], whf[c], acc[r][c], 0, 0, 0);
            }
    }

    int row0 = blockIdx.x * 128;
    int col0 = blockIdx.y * 128;
    #pragma unroll
    for (int r = 0; r < 4; ++r) {
        int mrow = row0 + wrow * 64 + r * 16 + (lane >> 4) * 4;
        #pragma unroll
        for (int c = 0; c < 4; ++c) {
            int n = col0 + wcol * 64 + c * 16 + (lane & 15);
            float* base = H + (size_t)(n >> 4) * (N_NODES * 16) + (n & 15);
            f32x4 v = acc[r][c];
            #pragma unroll
            for (int g = 0; g < 4; ++g)
                if (mrow + g < N_NODES)
                    base[(size_t)(mrow + g) * 16] = v[g];
        }
    }
}

// ---------------- BN prep (bias folded) ----------------
__global__ void k_bnprep(const float* __restrict__ gamma, const float* __restrict__ beta,
                         const float* __restrict__ mean, const float* __restrict__ var,
                         const float* __restrict__ bias,
                         float* __restrict__ scale, float* __restrict__ shift) {
    int l = blockIdx.x;
    int c = threadIdx.x;
    if (c < HID) {
        float s = gamma[l * HID + c] * rsqrtf(var[l * HID + c] + BN_EPS);
        scale[l * HID + c] = s;
        shift[l * HID + c] = beta[l * HID + c] + (bias[l * HID + c] - mean[l * HID + c]) * s;
    }
}

// ---------------- chunked gather: XCD-affine slices, sorted slots, coalesced edata ----------------
// One chunk per block (3.2 MB slice in XCD L2); unroll 8 for outstanding H lines.
#define GNB 782  // ceil(50000/64) slot-blocks per chunk

#define EDGE_FMA(E, V) \
    { float wght = __int_as_float(E.y); \
      acc.x = fmaf(V.x, wght, acc.x); acc.y = fmaf(V.y, wght, acc.y); \
      acc.z = fmaf(V.z, wght, acc.z); acc.w = fmaf(V.w, wght, acc.w); }

__device__ __forceinline__ float4 gather_quad(const float* __restrict__ Hc,
                                              const int2* __restrict__ edata,
                                              const float* __restrict__ selfn,
                                              float4 sc, float4 sh,
                                              int2 m, int node, int q4) {
    int stride = m.y & 0xFFFFF;
    int deg = m.y >> 20;
    const int2* ep = edata + m.x;
    float sn = selfn[node];
    float4 h = *(const float4*)(Hc + (size_t)node * 16 + q4);
    float4 acc;
    acc.x = h.x * sn; acc.y = h.y * sn; acc.z = h.z * sn; acc.w = h.w * sn;
    int j = 0;
    for (; j + 7 < deg; j += 8) {
        int2 e0 = ep[(size_t)(j + 0) * stride];
        int2 e1 = ep[(size_t)(j + 1) * stride];
        int2 e2 = ep[(size_t)(j + 2) * stride];
        int2 e3 = ep[(size_t)(j + 3) * stride];
        int2 e4 = ep[(size_t)(j + 4) * stride];
        int2 e5 = ep[(size_t)(j + 5) * stride];
        int2 e6 = ep[(size_t)(j + 6) * stride];
        int2 e7 = ep[(size_t)(j + 7) * stride];
        float4 v0 = *(const float4*)(Hc + (size_t)e0.x * 16 + q4);
        float4 v1 = *(const float4*)(Hc + (size_t)e1.x * 16 + q4);
        float4 v2 = *(const float4*)(Hc + (size_t)e2.x * 16 + q4);
        float4 v3 = *(const float4*)(Hc + (size_t)e3.x * 16 + q4);
        float4 v4 = *(const float4*)(Hc + (size_t)e4.x * 16 + q4);
        float4 v5 = *(const float4*)(Hc + (size_t)e5.x * 16 + q4);
        float4 v6 = *(const float4*)(Hc + (size_t)e6.x * 16 + q4);
        float4 v7 = *(const float4*)(Hc + (size_t)e7.x * 16 + q4);
        EDGE_FMA(e0, v0) EDGE_FMA(e1, v1) EDGE_FMA(e2, v2) EDGE_FMA(e3, v3)
        EDGE_FMA(e4, v4) EDGE_FMA(e5, v5) EDGE_FMA(e6, v6) EDGE_FMA(e7, v7)
    }
    for (; j + 3 < deg; j += 4) {
        int2 e0 = ep[(size_t)(j + 0) * stride];
        int2 e1 = ep[(size_t)(j + 1) * stride];
        int2 e2 = ep[(size_t)(j + 2) * stride];
        int2 e3 = ep[(size_t)(j + 3) * stride];
        float4 v0 = *(const float4*)(Hc + (size_t)e0.x * 16 + q4);
        float4 v1 = *(const float4*)(Hc + (size_t)e1.x * 16 + q4);
        float4 v2 = *(const float4*)(Hc + (size_t)e2.x * 16 + q4);
        float4 v3 = *(const float4*)(Hc + (size_t)e3.x * 16 + q4);
        EDGE_FMA(e0, v0) EDGE_FMA(e1, v1) EDGE_FMA(e2, v2) EDGE_FMA(e3, v3)
    }
    for (; j < deg; ++j) {
        int2 e0 = ep[(size_t)j * stride];
        float4 v0 = *(const float4*)(Hc + (size_t)e0.x * 16 + q4);
        EDGE_FMA(e0, v0)
    }
    float4 o;
    o.x = fmaxf(fmaf(acc.x, sc.x, sh.x), 0.f);
    o.y = fmaxf(fmaf(acc.y, sc.y, sh.y), 0.f);
    o.z = fmaxf(fmaf(acc.z, sc.z, sh.z), 0.f);
    o.w = fmaxf(fmaf(acc.w, sc.w, sh.w), 0.f);
    return o;
}

// variant A: bf16 hi/lo in FRAG ORDER (feeds next GEMM, KS=8)
__global__ __launch_bounds__(256) void k_gather_bf(const float* __restrict__ H,
                                                   const int2* __restrict__ meta,
                                                   const int2* __restrict__ edata,
                                                   const int* __restrict__ perm,
                                                   const float* __restrict__ selfn,
                                                   const float* __restrict__ bnscale,
                                                   const float* __restrict__ bnshift,
                                                   ushort_t* __restrict__ Xh,
                                                   ushort_t* __restrict__ Xl) {
    int bid = blockIdx.x;
    int x8 = bid & 7;
    int rest = bid >> 3;
    int phase = (rest >= GNB) ? 1 : 0;
    int nb = rest - phase * GNB;
    int chunk = phase * 8 + x8;
    const float* Hc = H + (size_t)chunk * (N_NODES * 16);
    int slot = nb * 64 + (threadIdx.x >> 2);
    if (slot >= N_NODES) return;
    int node = perm[slot];
    int2 m = meta[slot];
    int q4 = (threadIdx.x & 3) * 4;
    float4 sc = *(const float4*)(bnscale + chunk * 16 + q4);
    float4 sh = *(const float4*)(bnshift + chunk * 16 + q4);
    float4 o = gather_quad(Hc, edata, selfn, sc, sh, m, node, q4);
    ushort4 h, l;
    h.x = f2bf_rn(o.x); l.x = f2bf_rn(o.x - bf2f(h.x));
    h.y = f2bf_rn(o.y); l.y = f2bf_rn(o.y - bf2f(h.y));
    h.z = f2bf_rn(o.z); l.z = f2bf_rn(o.z - bf2f(h.z));
    h.w = f2bf_rn(o.w); l.w = f2bf_rn(o.w - bf2f(h.w));
    // fragment-order address (K=256, KS=8)
    int rf = node >> 4, mm = node & 15;
    int k0 = chunk * 16 + q4;
    int ks = k0 >> 5, qq = (k0 >> 3) & 3, j0 = k0 & 7;
    size_t oi = ((size_t)(rf * 8 + ks) * 64 + qq * 16 + mm) * 8 + j0;
    u32x2 hv, lv;
    hv.x = ((unsigned int)h.y << 16) | h.x;
    hv.y = ((unsigned int)h.w << 16) | h.z;
    lv.x = ((unsigned int)l.y << 16) | l.x;
    lv.y = ((unsigned int)l.w << 16) | l.z;
    __builtin_nontemporal_store(hv, (u32x2*)(Xh + oi));
    __builtin_nontemporal_store(lv, (u32x2*)(Xl + oi));
}

// variant B: fp32 chunk-major (last layer, feeds pool)
__global__ __launch_bounds__(256) void k_gather_f32(const float* __restrict__ H,
                                                    const int2* __restrict__ meta,
                                                    const int2* __restrict__ edata,
                                                    const int* __restrict__ perm,
                                                    const float* __restrict__ selfn,
                                                    const float* __restrict__ bnscale,
                                                    const float* __restrict__ bnshift,
                                                    float* __restrict__ X) {
    int bid = blockIdx.x;
    int x8 = bid & 7;
    int rest = bid >> 3;
    int phase = (rest >= GNB) ? 1 : 0;
    int nb = rest - phase * GNB;
    int chunk = phase * 8 + x8;
    const float* Hc = H + (size_t)chunk * (N_NODES * 16);
    float* Xc = X + (size_t)chunk * (N_NODES * 16);
    int slot = nb * 64 + (threadIdx.x >> 2);
    if (slot >= N_NODES) return;
    int node = perm[slot];
    int2 m = meta[slot];
    int q4 = (threadIdx.x & 3) * 4;
    float4 sc = *(const float4*)(bnscale + chunk * 16 + q4);
    float4 sh = *(const float4*)(bnshift + chunk * 16 + q4);
    float4 o = gather_quad(Hc, edata, selfn, sc, sh, m, node, q4);
    f32x4 ov;
    ov.x = o.x; ov.y = o.y; ov.z = o.z; ov.w = o.w;
    __builtin_nontemporal_store(ov, (f32x4*)(Xc + (size_t)node * 16 + q4));
}

// ---------------- segmented mean pool (X is chunk-major) ----------------
#define POOL_SPAN 25
__global__ __launch_bounds__(256) void k_pool(const float* __restrict__ X,
                                              const int* __restrict__ batch,
                                              float* __restrict__ pooled,
                                              int* __restrict__ cnt, int N) {
    int n0 = blockIdx.x * POOL_SPAN;
    int c = threadIdx.x;
    const float* Xc = X + (size_t)(c >> 4) * (N_NODES * 16) + (c & 15);
    int nend = min(n0 + POOL_SPAN, N);
    float acc = 0.f;
    int curg = batch[n0];
    int segcnt = 0;
    for (int n = n0; n < nend; ++n) {
        int g = batch[n];
        if (g != curg) {
            atomicAdd(&pooled[(size_t)curg * HID + c], acc);
            if (c == 0) atomicAdd(&cnt[curg], segcnt);
            acc = 0.f;
            segcnt = 0;
            curg = g;
        }
        acc += Xc[(size_t)n * 16];
        ++segcnt;
    }
    atomicAdd(&pooled[(size_t)curg * HID + c], acc);
    if (c == 0) atomicAdd(&cnt[curg], segcnt);
}

// ---------------- MLP head ----------------
__global__ __launch_bounds__(128) void k_mlp(const float* __restrict__ pooled,
                                             const int* __restrict__ cnt,
                                             const float* __restrict__ W1,
                                             const float* __restrict__ b1,
                                             const float* __restrict__ W2,
                                             const float* __restrict__ b2,
                                             float* __restrict__ out) {
    __shared__ float prow[HID];
    __shared__ float hred[2];
    int g = blockIdx.x;
    int j = threadIdx.x;
    prow[j] = pooled[(size_t)g * HID + j];
    prow[j + 128] = pooled[(size_t)g * HID + 128 + j];
    __syncthreads();
    float acc = 0.f;
    #pragma unroll 8
    for (int k = 0; k < HID; ++k) acc += prow[k] * W1[k * 128 + j];
    float inv = 1.0f / fmaxf((float)cnt[g], 1.0f);
    float h = fmaxf(acc * inv + b1[j], 0.f);
    float p = h * W2[j];
    #pragma unroll
    for (int off = 32; off > 0; off >>= 1) p += __shfl_down(p, off, 64);
    if ((j & 63) == 0) hred[j >> 6] = p;
    __syncthreads();
    if (j == 0) out[g] = hred[0] + hred[1] + b2[0];
}

extern "C" void kernel_launch(void* const* d_in, const int* in_sizes, int n_in,
                              void* d_out, int out_size, void* d_ws, size_t ws_size,
                              hipStream_t stream) {
    const float* x      = (const float*)d_in[0];
    const int*   ei     = (const int*)d_in[1];
    const int*   batch  = (const int*)d_in[2];
    const float* convW0 = (const float*)d_in[3];
    const float* convWs = (const float*)d_in[4];
    const float* convB  = (const float*)d_in[5];
    const float* gamma  = (const float*)d_in[6];
    const float* beta   = (const float*)d_in[7];
    const float* mean   = (const float*)d_in[8];
    const float* var    = (const float*)d_in[9];
    const float* lin1W  = (const float*)d_in[10];
    const float* lin1b  = (const float*)d_in[11];
    const float* lin2W  = (const float*)d_in[12];
    const float* lin2b  = (const float*)d_in[13];
    float* out = (float*)d_out;

    const int* src = ei;
    const int* dst = ei + N_EDGES;

    const int WTOT = 128 * 256 + 3 * 256 * 256; // 229376

    float* ws = (float*)d_ws;
    float* xbuf = ws;                                    // N*HID fp32 (layer3 out, chunk-major)
    float* hbuf = xbuf + (size_t)N_NODES * HID;          // N*HID fp32 (H, chunk-major)
    ushort_t* Ahb = (ushort_t*)(hbuf + (size_t)N_NODES * HID); // N*HID (frag order)
    ushort_t* Alb = Ahb + (size_t)N_NODES * HID;         // N*HID (frag order)
    ushort_t* WhT = Alb + (size_t)N_NODES * HID;         // WTOT (frag order)
    ushort_t* WlT = WhT + WTOT;                          // WTOT (frag order)
    float* dinv    = (float*)(WlT + WTOT);               // N
    float* selfn   = dinv + N_NODES;                     // N
    float* pooled  = selfn + N_NODES;                    // G*HID
    float* bnscale = pooled + (size_t)N_GRAPHS * HID;    // 4*HID
    float* bnshift = bnscale + N_LAYERS * HID;           // 4*HID
    int*   cnt     = (int*)(bnshift + N_LAYERS * HID);   // G
    int*   degi    = cnt + N_GRAPHS;                     // N
    int*   cursor  = degi + N_NODES;                     // N
    int*   perm    = cursor + N_NODES;                   // N
    int*   invperm = perm + N_NODES;                     // N
    int*   bins    = invperm + N_NODES;                  // NBIN
    int*   binstart= bins + NBIN;                        // NBIN
    int*   bincur  = binstart + NBIN;                    // NBIN
    int*   edgebase= bincur + NBIN;                      // NBIN
    int2*  meta    = (int2*)(edgebase + NBIN);           // N int2
    int2*  edata   = meta + N_NODES;                     // E int2

    hipMemsetAsync(degi, 0, (size_t)N_NODES * 4, stream);
    hipMemsetAsync(bins, 0, (size_t)NBIN * 4, stream);
    hipMemsetAsync(pooled, 0, (size_t)N_GRAPHS * HID * 4, stream);
    hipMemsetAsync(cnt, 0, (size_t)N_GRAPHS * 4, stream);

    // CSR build + norms + degree sort (all parallel; closed-form offsets)
    k_deg<<<(N_EDGES + 255) / 256, 256, 0, stream>>>(dst, degi, N_EDGES);
    k_nodenorm<<<(N_NODES + 255) / 256, 256, 0, stream>>>(degi, dinv, selfn, N_NODES);
    k_hist<<<(N_NODES + 255) / 256, 256, 0, stream>>>(degi, bins, N_NODES);
    k_binscan<<<1, 64, 0, stream>>>(bins, binstart, bincur, edgebase);
    k_assign<<<(N_NODES + 255) / 256, 256, 0, stream>>>(degi, binstart, edgebase, bins, bincur,
                                                        perm, invperm, meta, cursor, N_NODES);
    k_fill<<<(N_EDGES + 255) / 256, 256, 0, stream>>>(src, dst, dinv, invperm, meta, cursor,
                                                      edata, N_EDGES);

    // prep
    k_bnprep<<<N_LAYERS, 256, 0, stream>>>(gamma, beta, mean, var, convB, bnscale, bnshift);
    k_splitw<<<(WTOT + 255) / 256, 256, 0, stream>>>(convW0, convWs, WhT, WlT);
    k_splitx<<<(N_NODES * IN_DIM / 4 + 255) / 256, 256, 0, stream>>>(x, Ahb, Alb, N_NODES * IN_DIM / 4);

    dim3 gg((NRF + 7) / 8, 2);
    for (int l = 0; l < N_LAYERS; ++l) {
        int KS = (l == 0) ? 4 : 8;
        size_t woff = (l == 0) ? 0 : (size_t)(32768 + (l - 1) * 65536);
        k_gemm<<<gg, 256, 0, stream>>>(Ahb, Alb, WhT + woff, WlT + woff, hbuf, KS);
        if (l < N_LAYERS - 1)
            k_gather_bf<<<16 * GNB, 256, 0, stream>>>(hbuf, meta, edata, perm, selfn,
                                                      bnscale + l * HID, bnshift + l * HID,
                                                      Ahb, Alb);
        else
            k_gather_f32<<<16 * GNB, 256, 0, stream>>>(hbuf, meta, edata, perm, selfn,
                                                       bnscale + l * HID, bnshift + l * HID,
                                                       xbuf);
    }

    k_pool<<<(N_NODES + POOL_SPAN - 1) / POOL_SPAN, 256, 0, stream>>>(xbuf, batch, pooled, cnt, N_NODES);
    k_mlp<<<N_GRAPHS, 128, 0, stream>>>(pooled, cnt, lin1W, lin1b, lin2W, lin2b, out);
}

// Round 16
// 717.439 us; speedup vs baseline: 1.1285x; 1.1285x over previous
//
#include <hip/hip_runtime.h>

#define N_NODES 50000
#define N_EDGES 800000
#define N_GRAPHS 2048
#define IN_DIM 128
#define HID 256
#define N_LAYERS 4
#define BN_EPS 1e-5f
#define NBIN 128

typedef unsigned short ushort_t;
typedef __bf16 bf16x8 __attribute__((ext_vector_type(8)));
typedef float f32x4 __attribute__((ext_vector_type(4)));
typedef unsigned int u32x2 __attribute__((ext_vector_type(2)));

// ---- fp32 -> bf16 (round-to-nearest-even) helpers ----
__device__ __forceinline__ ushort_t f2bf_rn(float x) {
    unsigned int u = __float_as_uint(x);
    u += 0x7FFFu + ((u >> 16) & 1u);
    return (ushort_t)(u >> 16);
}
__device__ __forceinline__ float bf2f(ushort_t h) {
    return __uint_as_float(((unsigned int)h) << 16);
}

// ---- async global->LDS, 16B per lane ----
__device__ __forceinline__ void gl_lds16(const ushort_t* g, ushort_t* l) {
    __builtin_amdgcn_global_load_lds(
        (const __attribute__((address_space(1))) void*)g,
        (__attribute__((address_space(3))) void*)l, 16, 0, 0);
}

// ---------------- degree count ----------------
__global__ void k_deg(const int* __restrict__ dst, int* __restrict__ degi, int E) {
    int e = blockIdx.x * blockDim.x + threadIdx.x;
    if (e < E) atomicAdd(&degi[dst[e]], 1);
}

__global__ void k_nodenorm(const int* __restrict__ degi, float* __restrict__ dinv,
                           float* __restrict__ selfn, int N) {
    int n = blockIdx.x * blockDim.x + threadIdx.x;
    if (n < N) {
        float d = 1.0f + (float)degi[n];
        dinv[n] = 1.0f / sqrtf(d);
        selfn[n] = 1.0f / d;
    }
}

// ---------------- degree histogram (hierarchical) ----------------
__global__ __launch_bounds__(256) void k_hist(const int* __restrict__ degi,
                                              int* __restrict__ bins, int N) {
    __shared__ int lbin[NBIN];
    int t = threadIdx.x;
    if (t < NBIN) lbin[t] = 0;
    __syncthreads();
    int n = blockIdx.x * 256 + t;
    if (n < N) atomicAdd(&lbin[min(degi[n], NBIN - 1)], 1);
    __syncthreads();
    if (t < NBIN && lbin[t] > 0) atomicAdd(&bins[t], lbin[t]);
}

// ---------------- bin prefix (tiny serial, 128 iters) ----------------
__global__ void k_binscan(const int* __restrict__ bins, int* __restrict__ binstart,
                          int* __restrict__ bincur, int* __restrict__ edgebase) {
    if (threadIdx.x == 0) {
        int run = 0, erun = 0;
        for (int d = 0; d < NBIN; ++d) {
            binstart[d] = run;
            bincur[d] = run;
            edgebase[d] = erun;
            run += bins[d];
            erun += bins[d] * d;
        }
    }
}

// ---------------- parallel slot assignment, hierarchical; emits per-slot meta ----------------
__global__ __launch_bounds__(256) void k_assign(const int* __restrict__ degi,
                                                const int* __restrict__ binstart,
                                                const int* __restrict__ edgebase,
                                                const int* __restrict__ bins,
                                                int* __restrict__ bincur,
                                                int* __restrict__ perm, int* __restrict__ invperm,
                                                int2* __restrict__ meta, int* __restrict__ cursor,
                                                int N) {
    __shared__ int lbin[NBIN];
    __shared__ int lbase[NBIN];
    int t = threadIdx.x;
    if (t < NBIN) lbin[t] = 0;
    __syncthreads();
    int n = blockIdx.x * 256 + t;
    int d = 0, lrank = 0;
    if (n < N) {
        d = min(degi[n], NBIN - 1);
        lrank = atomicAdd(&lbin[d], 1);
    }
    __syncthreads();
    if (t < NBIN && lbin[t] > 0) lbase[t] = atomicAdd(&bincur[t], lbin[t]);
    __syncthreads();
    if (n < N) {
        int slot = lbase[d] + lrank;
        perm[slot] = n;
        invperm[n] = slot;
        int2 m;
        m.x = edgebase[d] + (slot - binstart[d]);
        m.y = bins[d] | (d << 20);
        meta[slot] = m;
        cursor[slot] = 0;
    }
}

// ---------------- CSR fill into bin-interleaved layout ----------------
__global__ void k_fill(const int* __restrict__ src, const int* __restrict__ dst,
                       const float* __restrict__ dinv, const int* __restrict__ invperm,
                       const int2* __restrict__ meta, int* __restrict__ cursor,
                       int2* __restrict__ edata, int E) {
    int e = blockIdx.x * blockDim.x + threadIdx.x;
    if (e >= E) return;
    int s = src[e], d = dst[e];
    int slot = invperm[d];
    int2 m = meta[slot];
    int j = atomicAdd(&cursor[slot], 1);
    int pos = m.x + j * (m.y & 0xFFFFF);
    int2 v;
    v.x = s;
    v.y = __float_as_int(dinv[s] * dinv[d]);
    edata[pos] = v;
}

// ---------------- x (node-major [N][128] fp32) -> chunk-major [8][N][16] fp32 ----------------
__global__ __launch_bounds__(256) void k_tochunk(const float* __restrict__ x,
                                                 float* __restrict__ Xc, int total4) {
    int i = blockIdx.x * blockDim.x + threadIdx.x;
    if (i >= total4) return;
    float4 v = ((const float4*)x)[i];
    int n = i >> 5;
    int c0 = (i & 31) * 4;
    float* p = Xc + (size_t)(c0 >> 4) * (N_NODES * 16) + (size_t)n * 16 + (c0 & 15);
    *(float4*)p = v;
}

// ---------------- split + transpose weights -> [layer][n][k] bf16 hi/lo ----------------
__global__ void k_splitw(const float* __restrict__ W0, const float* __restrict__ Ws,
                         ushort_t* __restrict__ Wh, ushort_t* __restrict__ Wl) {
    int i = blockIdx.x * blockDim.x + threadIdx.x;
    const int total = 128 * 256 + 3 * 256 * 256;
    if (i >= total) return;
    float v;
    if (i < 32768) {
        int n = i >> 7, k = i & 127;
        v = W0[k * 256 + n];
    } else {
        int t = i - 32768;
        int l = t >> 16;
        int r = t & 65535;
        int n = r >> 8, k = r & 255;
        v = Ws[l * 65536 + k * 256 + n];
    }
    ushort_t h = f2bf_rn(v);
    Wh[i] = h;
    Wl[i] = f2bf_rn(v - bf2f(h));
}

// ---------------- MFMA split-bf16 GEMM + fused BN/ReLU epilogue ----------------
// A = aggregated features (bf16 hi/lo node-major [N][K]); W node-major [256][K].
// Output X = relu((A W)*scale + shift) in CHUNK-MAJOR [16][N][16].
__global__ __launch_bounds__(256) void k_gemm(const ushort_t* __restrict__ Ah,
                                              const ushort_t* __restrict__ Al,
                                              const ushort_t* __restrict__ Wh,
                                              const ushort_t* __restrict__ Wl,
                                              const float* __restrict__ bnscale,
                                              const float* __restrict__ bnshift,
                                              float* __restrict__ X, int K) {
    __shared__ ushort_t sm[4 * 128 * 32];
    ushort_t* tAh = sm;
    ushort_t* tAl = sm + 4096;
    ushort_t* tWh = sm + 8192;
    ushort_t* tWl = sm + 12288;

    int tid = threadIdx.x;
    int lane = tid & 63;
    int w = tid >> 6;
    int wrow = w & 1, wcol = w >> 1;
    int row0 = blockIdx.x * 128;
    int col0 = blockIdx.y * 128;

    const ushort_t* gsrc = (w == 0) ? Ah : (w == 1) ? Al : (w == 2) ? Wh : Wl;
    int rbase = (w < 2) ? row0 : col0;
    int rlimit = (w < 2) ? N_NODES : (col0 + 128);
    ushort_t* ldst = sm + w * 4096;
    int srow = lane >> 2;
    int sch = lane & 3;

    f32x4 acc[4][4] = {};
    int m = lane & 15, q = lane >> 4;

    for (int k0 = 0; k0 < K; k0 += 32) {
        #pragma unroll
        for (int i = 0; i < 8; ++i) {
            int r = i * 16 + srow;
            int grow = rbase + r;
            int gch = sch ^ (r & 3);
            if (grow < rlimit)
                gl_lds16(gsrc + (size_t)grow * K + k0 + gch * 8, ldst + i * 512);
        }
        __syncthreads();

        bf16x8 ahf[4], alf[4], whf[4], wlf[4];
        #pragma unroll
        for (int r = 0; r < 4; ++r) {
            int rr = wrow * 64 + r * 16 + m;
            int off = rr * 32 + ((q ^ (rr & 3)) << 3);
            ahf[r] = *(const bf16x8*)(tAh + off);
            alf[r] = *(const bf16x8*)(tAl + off);
        }
        #pragma unroll
        for (int c = 0; c < 4; ++c) {
            int nn = wcol * 64 + c * 16 + m;
            int off = nn * 32 + ((q ^ (nn & 3)) << 3);
            whf[c] = *(const bf16x8*)(tWh + off);
            wlf[c] = *(const bf16x8*)(tWl + off);
        }
        #pragma unroll
        for (int r = 0; r < 4; ++r)
            #pragma unroll
            for (int c = 0; c < 4; ++c) {
                acc[r][c] = __builtin_amdgcn_mfma_f32_16x16x32_bf16(ahf[r], whf[c], acc[r][c], 0, 0, 0);
                acc[r][c] = __builtin_amdgcn_mfma_f32_16x16x32_bf16(ahf[r], wlf[c], acc[r][c], 0, 0, 0);
                acc[r][c] = __builtin_amdgcn_mfma_f32_16x16x32_bf16(alf[r], whf[c], acc[r][c], 0, 0, 0);
            }
        __syncthreads();
    }

    #pragma unroll
    for (int r = 0; r < 4; ++r) {
        int mrow = row0 + wrow * 64 + r * 16 + (lane >> 4) * 4;
        #pragma unroll
        for (int c = 0; c < 4; ++c) {
            int n = col0 + wcol * 64 + c * 16 + (lane & 15);
            float sc = bnscale[n];
            float sh = bnshift[n];
            float* base = X + (size_t)(n >> 4) * (N_NODES * 16) + (n & 15);
            f32x4 v = acc[r][c];
            #pragma unroll
            for (int g = 0; g < 4; ++g)
                if (mrow + g < N_NODES)
                    base[(size_t)(mrow + g) * 16] = fmaxf(fmaf(v[g], sc, sh), 0.f);
        }
    }
}

// ---------------- BN prep (bias folded) ----------------
__global__ void k_bnprep(const float* __restrict__ gamma, const float* __restrict__ beta,
                         const float* __restrict__ mean, const float* __restrict__ var,
                         const float* __restrict__ bias,
                         float* __restrict__ scale, float* __restrict__ shift) {
    int l = blockIdx.x;
    int c = threadIdx.x;
    if (c < HID) {
        float s = gamma[l * HID + c] * rsqrtf(var[l * HID + c] + BN_EPS);
        scale[l * HID + c] = s;
        shift[l * HID + c] = beta[l * HID + c] + (bias[l * HID + c] - mean[l * HID + c]) * s;
    }
}

// ---------------- chunked gather: pure linear aggregation Âx -> bf16 hi/lo node-major ----------------
// One chunk per block (3.2 MB slice in XCD L2); sorted slots; coalesced column-major edata.
#define GNB 782  // ceil(50000/64) slot-blocks per chunk

#define EDGE_FMA(E, V) \
    { float wght = __int_as_float(E.y); \
      acc.x = fmaf(V.x, wght, acc.x); acc.y = fmaf(V.y, wght, acc.y); \
      acc.z = fmaf(V.z, wght, acc.z); acc.w = fmaf(V.w, wght, acc.w); }

__global__ __launch_bounds__(256) void k_gather(const float* __restrict__ Xc,
                                                const int2* __restrict__ meta,
                                                const int2* __restrict__ edata,
                                                const int* __restrict__ perm,
                                                const float* __restrict__ selfn,
                                                ushort_t* __restrict__ Ah,
                                                ushort_t* __restrict__ Al, int nchunk) {
    int bid = blockIdx.x;
    int x8 = bid & 7;
    int rest = bid >> 3;
    int phase = (nchunk == 16 && rest >= GNB) ? 1 : 0;
    int nb = rest - phase * GNB;
    int chunk = phase * 8 + x8;
    const float* Hc = Xc + (size_t)chunk * (N_NODES * 16);
    int slot = nb * 64 + (threadIdx.x >> 2);
    if (slot >= N_NODES) return;
    int node = perm[slot];
    int2 m = meta[slot];
    int q4 = (threadIdx.x & 3) * 4;

    int stride = m.y & 0xFFFFF;
    int deg = m.y >> 20;
    const int2* ep = edata + m.x;
    float sn = selfn[node];
    float4 h = *(const float4*)(Hc + (size_t)node * 16 + q4);
    float4 acc;
    acc.x = h.x * sn; acc.y = h.y * sn; acc.z = h.z * sn; acc.w = h.w * sn;
    int j = 0;
    for (; j + 7 < deg; j += 8) {
        int2 e0 = ep[(size_t)(j + 0) * stride];
        int2 e1 = ep[(size_t)(j + 1) * stride];
        int2 e2 = ep[(size_t)(j + 2) * stride];
        int2 e3 = ep[(size_t)(j + 3) * stride];
        int2 e4 = ep[(size_t)(j + 4) * stride];
        int2 e5 = ep[(size_t)(j + 5) * stride];
        int2 e6 = ep[(size_t)(j + 6) * stride];
        int2 e7 = ep[(size_t)(j + 7) * stride];
        float4 v0 = *(const float4*)(Hc + (size_t)e0.x * 16 + q4);
        float4 v1 = *(const float4*)(Hc + (size_t)e1.x * 16 + q4);
        float4 v2 = *(const float4*)(Hc + (size_t)e2.x * 16 + q4);
        float4 v3 = *(const float4*)(Hc + (size_t)e3.x * 16 + q4);
        float4 v4 = *(const float4*)(Hc + (size_t)e4.x * 16 + q4);
        float4 v5 = *(const float4*)(Hc + (size_t)e5.x * 16 + q4);
        float4 v6 = *(const float4*)(Hc + (size_t)e6.x * 16 + q4);
        float4 v7 = *(const float4*)(Hc + (size_t)e7.x * 16 + q4);
        EDGE_FMA(e0, v0) EDGE_FMA(e1, v1) EDGE_FMA(e2, v2) EDGE_FMA(e3, v3)
        EDGE_FMA(e4, v4) EDGE_FMA(e5, v5) EDGE_FMA(e6, v6) EDGE_FMA(e7, v7)
    }
    for (; j + 3 < deg; j += 4) {
        int2 e0 = ep[(size_t)(j + 0) * stride];
        int2 e1 = ep[(size_t)(j + 1) * stride];
        int2 e2 = ep[(size_t)(j + 2) * stride];
        int2 e3 = ep[(size_t)(j + 3) * stride];
        float4 v0 = *(const float4*)(Hc + (size_t)e0.x * 16 + q4);
        float4 v1 = *(const float4*)(Hc + (size_t)e1.x * 16 + q4);
        float4 v2 = *(const float4*)(Hc + (size_t)e2.x * 16 + q4);
        float4 v3 = *(const float4*)(Hc + (size_t)e3.x * 16 + q4);
        EDGE_FMA(e0, v0) EDGE_FMA(e1, v1) EDGE_FMA(e2, v2) EDGE_FMA(e3, v3)
    }
    for (; j < deg; ++j) {
        int2 e0 = ep[(size_t)j * stride];
        float4 v0 = *(const float4*)(Hc + (size_t)e0.x * 16 + q4);
        EDGE_FMA(e0, v0)
    }

    ushort4 hq, lq;
    hq.x = f2bf_rn(acc.x); lq.x = f2bf_rn(acc.x - bf2f(hq.x));
    hq.y = f2bf_rn(acc.y); lq.y = f2bf_rn(acc.y - bf2f(hq.y));
    hq.z = f2bf_rn(acc.z); lq.z = f2bf_rn(acc.z - bf2f(hq.z));
    hq.w = f2bf_rn(acc.w); lq.w = f2bf_rn(acc.w - bf2f(hq.w));
    size_t oi = (size_t)node * (nchunk * 16) + chunk * 16 + q4;
    u32x2 hv, lv;
    hv.x = ((unsigned int)hq.y << 16) | hq.x;
    hv.y = ((unsigned int)hq.w << 16) | hq.z;
    lv.x = ((unsigned int)lq.y << 16) | lq.x;
    lv.y = ((unsigned int)lq.w << 16) | lq.z;
    __builtin_nontemporal_store(hv, (u32x2*)(Ah + oi));
    __builtin_nontemporal_store(lv, (u32x2*)(Al + oi));
}

// ---------------- segmented mean pool (X is chunk-major) ----------------
#define POOL_SPAN 25
__global__ __launch_bounds__(256) void k_pool(const float* __restrict__ X,
                                              const int* __restrict__ batch,
                                              float* __restrict__ pooled,
                                              int* __restrict__ cnt, int N) {
    int n0 = blockIdx.x * POOL_SPAN;
    int c = threadIdx.x;
    const float* Xc = X + (size_t)(c >> 4) * (N_NODES * 16) + (c & 15);
    int nend = min(n0 + POOL_SPAN, N);
    float acc = 0.f;
    int curg = batch[n0];
    int segcnt = 0;
    for (int n = n0; n < nend; ++n) {
        int g = batch[n];
        if (g != curg) {
            atomicAdd(&pooled[(size_t)curg * HID + c], acc);
            if (c == 0) atomicAdd(&cnt[curg], segcnt);
            acc = 0.f;
            segcnt = 0;
            curg = g;
        }
        acc += Xc[(size_t)n * 16];
        ++segcnt;
    }
    atomicAdd(&pooled[(size_t)curg * HID + c], acc);
    if (c == 0) atomicAdd(&cnt[curg], segcnt);
}

// ---------------- MLP head ----------------
__global__ __launch_bounds__(128) void k_mlp(const float* __restrict__ pooled,
                                             const int* __restrict__ cnt,
                                             const float* __restrict__ W1,
                                             const float* __restrict__ b1,
                                             const float* __restrict__ W2,
                                             const float* __restrict__ b2,
                                             float* __restrict__ out) {
    __shared__ float prow[HID];
    __shared__ float hred[2];
    int g = blockIdx.x;
    int j = threadIdx.x;
    prow[j] = pooled[(size_t)g * HID + j];
    prow[j + 128] = pooled[(size_t)g * HID + 128 + j];
    __syncthreads();
    float acc = 0.f;
    #pragma unroll 8
    for (int k = 0; k < HID; ++k) acc += prow[k] * W1[k * 128 + j];
    float inv = 1.0f / fmaxf((float)cnt[g], 1.0f);
    float h = fmaxf(acc * inv + b1[j], 0.f);
    float p = h * W2[j];
    #pragma unroll
    for (int off = 32; off > 0; off >>= 1) p += __shfl_down(p, off, 64);
    if ((j & 63) == 0) hred[j >> 6] = p;
    __syncthreads();
    if (j == 0) out[g] = hred[0] + hred[1] + b2[0];
}

extern "C" void kernel_launch(void* const* d_in, const int* in_sizes, int n_in,
                              void* d_out, int out_size, void* d_ws, size_t ws_size,
                              hipStream_t stream) {
    const float* x      = (const float*)d_in[0];
    const int*   ei     = (const int*)d_in[1];
    const int*   batch  = (const int*)d_in[2];
    const float* convW0 = (const float*)d_in[3];
    const float* convWs = (const float*)d_in[4];
    const float* convB  = (const float*)d_in[5];
    const float* gamma  = (const float*)d_in[6];
    const float* beta   = (const float*)d_in[7];
    const float* mean   = (const float*)d_in[8];
    const float* var    = (const float*)d_in[9];
    const float* lin1W  = (const float*)d_in[10];
    const float* lin1b  = (const float*)d_in[11];
    const float* lin2W  = (const float*)d_in[12];
    const float* lin2b  = (const float*)d_in[13];
    float* out = (float*)d_out;

    const int* src = ei;
    const int* dst = ei + N_EDGES;

    const int WTOT = 128 * 256 + 3 * 256 * 256; // 229376

    float* ws = (float*)d_ws;
    float* xbuf = ws;                                    // N*HID fp32 chunk-major (ping)
    float* hbuf = xbuf + (size_t)N_NODES * HID;          // N*HID fp32 chunk-major (pong)
    ushort_t* Ahb = (ushort_t*)(hbuf + (size_t)N_NODES * HID); // N*HID
    ushort_t* Alb = Ahb + (size_t)N_NODES * HID;         // N*HID
    ushort_t* WhT = Alb + (size_t)N_NODES * HID;         // WTOT
    ushort_t* WlT = WhT + WTOT;                          // WTOT
    float* dinv    = (float*)(WlT + WTOT);               // N
    float* selfn   = dinv + N_NODES;                     // N
    float* pooled  = selfn + N_NODES;                    // G*HID
    float* bnscale = pooled + (size_t)N_GRAPHS * HID;    // 4*HID
    float* bnshift = bnscale + N_LAYERS * HID;           // 4*HID
    int*   cnt     = (int*)(bnshift + N_LAYERS * HID);   // G
    int*   degi    = cnt + N_GRAPHS;                     // N
    int*   cursor  = degi + N_NODES;                     // N
    int*   perm    = cursor + N_NODES;                   // N
    int*   invperm = perm + N_NODES;                     // N
    int*   bins    = invperm + N_NODES;                  // NBIN
    int*   binstart= bins + NBIN;                        // NBIN
    int*   bincur  = binstart + NBIN;                    // NBIN
    int*   edgebase= bincur + NBIN;                      // NBIN
    int2*  meta    = (int2*)(edgebase + NBIN);           // N int2
    int2*  edata   = meta + N_NODES;                     // E int2

    hipMemsetAsync(degi, 0, (size_t)N_NODES * 4, stream);
    hipMemsetAsync(bins, 0, (size_t)NBIN * 4, stream);
    hipMemsetAsync(pooled, 0, (size_t)N_GRAPHS * HID * 4, stream);
    hipMemsetAsync(cnt, 0, (size_t)N_GRAPHS * 4, stream);

    // CSR build + norms + degree sort (all parallel; closed-form offsets)
    k_deg<<<(N_EDGES + 255) / 256, 256, 0, stream>>>(dst, degi, N_EDGES);
    k_nodenorm<<<(N_NODES + 255) / 256, 256, 0, stream>>>(degi, dinv, selfn, N_NODES);
    k_hist<<<(N_NODES + 255) / 256, 256, 0, stream>>>(degi, bins, N_NODES);
    k_binscan<<<1, 64, 0, stream>>>(bins, binstart, bincur, edgebase);
    k_assign<<<(N_NODES + 255) / 256, 256, 0, stream>>>(degi, binstart, edgebase, bins, bincur,
                                                        perm, invperm, meta, cursor, N_NODES);
    k_fill<<<(N_EDGES + 255) / 256, 256, 0, stream>>>(src, dst, dinv, invperm, meta, cursor,
                                                      edata, N_EDGES);

    // prep
    k_bnprep<<<N_LAYERS, 256, 0, stream>>>(gamma, beta, mean, var, convB, bnscale, bnshift);
    k_splitw<<<(WTOT + 255) / 256, 256, 0, stream>>>(convW0, convWs, WhT, WlT);
    k_tochunk<<<(N_NODES * IN_DIM / 4 + 255) / 256, 256, 0, stream>>>(x, xbuf, N_NODES * IN_DIM / 4);

    // layers: gather (Âx) -> GEMM (+BN+ReLU epilogue, chunk-major out), ping-pong buffers
    dim3 gg((N_NODES + 127) / 128, 2);
    float* cur = xbuf;
    for (int l = 0; l < N_LAYERS; ++l) {
        int nchunk = (l == 0) ? (IN_DIM / 16) : (HID / 16);
        int K = nchunk * 16;
        size_t woff = (l == 0) ? 0 : (size_t)(32768 + (l - 1) * 65536);
        k_gather<<<nchunk * GNB, 256, 0, stream>>>(cur, meta, edata, perm, selfn,
                                                   Ahb, Alb, nchunk);
        float* nxt = (cur == xbuf) ? hbuf : xbuf;
        k_gemm<<<gg, 256, 0, stream>>>(Ahb, Alb, WhT + woff, WlT + woff,
                                       bnscale + l * HID, bnshift + l * HID, nxt, K);
        cur = nxt;
    }

    k_pool<<<(N_NODES + POOL_SPAN - 1) / POOL_SPAN, 256, 0, stream>>>(cur, batch, pooled, cnt, N_NODES);
    k_mlp<<<N_GRAPHS, 128, 0, stream>>>(pooled, cnt, lin1W, lin1b, lin2W, lin2b, out);
}

// Round 17
// 578.967 us; speedup vs baseline: 1.3984x; 1.2392x over previous
//
#include <hip/hip_runtime.h>

#define N_NODES 50000
#define N_EDGES 800000
#define N_GRAPHS 2048
#define IN_DIM 128
#define HID 256
#define N_LAYERS 4
#define BN_EPS 1e-5f
#define NBIN 128

typedef unsigned short ushort_t;
typedef __bf16 bf16x8 __attribute__((ext_vector_type(8)));
typedef float f32x4 __attribute__((ext_vector_type(4)));
typedef unsigned int u32x2 __attribute__((ext_vector_type(2)));
typedef unsigned int u32x4 __attribute__((ext_vector_type(4)));
typedef _Float16 f16x8 __attribute__((ext_vector_type(8)));
typedef _Float16 f16x4 __attribute__((ext_vector_type(4)));

// ---- fp32 -> bf16 (round-to-nearest-even) helpers ----
__device__ __forceinline__ ushort_t f2bf_rn(float x) {
    unsigned int u = __float_as_uint(x);
    u += 0x7FFFu + ((u >> 16) & 1u);
    return (ushort_t)(u >> 16);
}
__device__ __forceinline__ float bf2f(ushort_t h) {
    return __uint_as_float(((unsigned int)h) << 16);
}

// ---- async global->LDS, 16B per lane ----
__device__ __forceinline__ void gl_lds16(const ushort_t* g, ushort_t* l) {
    __builtin_amdgcn_global_load_lds(
        (const __attribute__((address_space(1))) void*)g,
        (__attribute__((address_space(3))) void*)l, 16, 0, 0);
}

// ---------------- degree count ----------------
__global__ void k_deg(const int* __restrict__ dst, int* __restrict__ degi, int E) {
    int e = blockIdx.x * blockDim.x + threadIdx.x;
    if (e < E) atomicAdd(&degi[dst[e]], 1);
}

__global__ void k_nodenorm(const int* __restrict__ degi, float* __restrict__ dinv,
                           float* __restrict__ selfn, int N) {
    int n = blockIdx.x * blockDim.x + threadIdx.x;
    if (n < N) {
        float d = 1.0f + (float)degi[n];
        dinv[n] = 1.0f / sqrtf(d);
        selfn[n] = 1.0f / d;
    }
}

// ---------------- degree histogram (hierarchical) ----------------
__global__ __launch_bounds__(256) void k_hist(const int* __restrict__ degi,
                                              int* __restrict__ bins, int N) {
    __shared__ int lbin[NBIN];
    int t = threadIdx.x;
    if (t < NBIN) lbin[t] = 0;
    __syncthreads();
    int n = blockIdx.x * 256 + t;
    if (n < N) atomicAdd(&lbin[min(degi[n], NBIN - 1)], 1);
    __syncthreads();
    if (t < NBIN && lbin[t] > 0) atomicAdd(&bins[t], lbin[t]);
}

// ---------------- bin prefix (tiny serial, 128 iters) ----------------
__global__ void k_binscan(const int* __restrict__ bins, int* __restrict__ binstart,
                          int* __restrict__ bincur, int* __restrict__ edgebase) {
    if (threadIdx.x == 0) {
        int run = 0, erun = 0;
        for (int d = 0; d < NBIN; ++d) {
            binstart[d] = run;
            bincur[d] = run;
            edgebase[d] = erun;
            run += bins[d];
            erun += bins[d] * d;
        }
    }
}

// ---------------- parallel slot assignment, hierarchical; emits per-slot meta ----------------
__global__ __launch_bounds__(256) void k_assign(const int* __restrict__ degi,
                                                const int* __restrict__ binstart,
                                                const int* __restrict__ edgebase,
                                                const int* __restrict__ bins,
                                                int* __restrict__ bincur,
                                                int* __restrict__ perm, int* __restrict__ invperm,
                                                int2* __restrict__ meta, int* __restrict__ cursor,
                                                int N) {
    __shared__ int lbin[NBIN];
    __shared__ int lbase[NBIN];
    int t = threadIdx.x;
    if (t < NBIN) lbin[t] = 0;
    __syncthreads();
    int n = blockIdx.x * 256 + t;
    int d = 0, lrank = 0;
    if (n < N) {
        d = min(degi[n], NBIN - 1);
        lrank = atomicAdd(&lbin[d], 1);
    }
    __syncthreads();
    if (t < NBIN && lbin[t] > 0) lbase[t] = atomicAdd(&bincur[t], lbin[t]);
    __syncthreads();
    if (n < N) {
        int slot = lbase[d] + lrank;
        perm[slot] = n;
        invperm[n] = slot;
        int2 m;
        m.x = edgebase[d] + (slot - binstart[d]);
        m.y = bins[d] | (d << 20);
        meta[slot] = m;
        cursor[slot] = 0;
    }
}

// ---------------- CSR fill into bin-interleaved layout ----------------
__global__ void k_fill(const int* __restrict__ src, const int* __restrict__ dst,
                       const float* __restrict__ dinv, const int* __restrict__ invperm,
                       const int2* __restrict__ meta, int* __restrict__ cursor,
                       int2* __restrict__ edata, int E) {
    int e = blockIdx.x * blockDim.x + threadIdx.x;
    if (e >= E) return;
    int s = src[e], d = dst[e];
    int slot = invperm[d];
    int2 m = meta[slot];
    int j = atomicAdd(&cursor[slot], 1);
    int pos = m.x + j * (m.y & 0xFFFFF);
    int2 v;
    v.x = s;
    v.y = __float_as_int(dinv[s] * dinv[d]);
    edata[pos] = v;
}

// ---------------- x (node-major [N][128] fp32) -> fp16 chunk-major [4][N][32] ----------------
__global__ __launch_bounds__(256) void k_tochunk(const float* __restrict__ x,
                                                 _Float16* __restrict__ X16, int total4) {
    int i = blockIdx.x * blockDim.x + threadIdx.x;
    if (i >= total4) return;
    float4 v = ((const float4*)x)[i];
    int n = i >> 5;
    int c0 = (i & 31) * 4;
    f16x4 o;
    o.x = (_Float16)v.x; o.y = (_Float16)v.y; o.z = (_Float16)v.z; o.w = (_Float16)v.w;
    *(f16x4*)(X16 + (size_t)(c0 >> 5) * (N_NODES * 32) + (size_t)n * 32 + (c0 & 31)) = o;
}

// ---------------- split + transpose weights -> [layer][n][k] bf16 hi/lo ----------------
__global__ void k_splitw(const float* __restrict__ W0, const float* __restrict__ Ws,
                         ushort_t* __restrict__ Wh, ushort_t* __restrict__ Wl) {
    int i = blockIdx.x * blockDim.x + threadIdx.x;
    const int total = 128 * 256 + 3 * 256 * 256;
    if (i >= total) return;
    float v;
    if (i < 32768) {
        int n = i >> 7, k = i & 127;
        v = W0[k * 256 + n];
    } else {
        int t = i - 32768;
        int l = t >> 16;
        int r = t & 65535;
        int n = r >> 8, k = r & 255;
        v = Ws[l * 65536 + k * 256 + n];
    }
    ushort_t h = f2bf_rn(v);
    Wh[i] = h;
    Wl[i] = f2bf_rn(v - bf2f(h));
}

// ---------------- MFMA split-bf16 GEMM + fused BN/ReLU epilogue ----------------
// A = aggregated features (bf16 hi/lo node-major [N][K]); W node-major [256][K].
// fp16_out=1: X16 = fp16 chunk-major [8][N][32]; else Xf = fp32 chunk-major [16][N][16].
__global__ __launch_bounds__(256) void k_gemm(const ushort_t* __restrict__ Ah,
                                              const ushort_t* __restrict__ Al,
                                              const ushort_t* __restrict__ Wh,
                                              const ushort_t* __restrict__ Wl,
                                              const float* __restrict__ bnscale,
                                              const float* __restrict__ bnshift,
                                              float* __restrict__ Xf,
                                              _Float16* __restrict__ X16,
                                              int K, int fp16_out) {
    __shared__ ushort_t sm[4 * 128 * 32];
    ushort_t* tAh = sm;
    ushort_t* tAl = sm + 4096;
    ushort_t* tWh = sm + 8192;
    ushort_t* tWl = sm + 12288;

    int tid = threadIdx.x;
    int lane = tid & 63;
    int w = tid >> 6;
    int wrow = w & 1, wcol = w >> 1;
    int row0 = blockIdx.x * 128;
    int col0 = blockIdx.y * 128;

    const ushort_t* gsrc = (w == 0) ? Ah : (w == 1) ? Al : (w == 2) ? Wh : Wl;
    int rbase = (w < 2) ? row0 : col0;
    int rlimit = (w < 2) ? N_NODES : (col0 + 128);
    ushort_t* ldst = sm + w * 4096;
    int srow = lane >> 2;
    int sch = lane & 3;

    f32x4 acc[4][4] = {};
    int m = lane & 15, q = lane >> 4;

    for (int k0 = 0; k0 < K; k0 += 32) {
        #pragma unroll
        for (int i = 0; i < 8; ++i) {
            int r = i * 16 + srow;
            int grow = rbase + r;
            int gch = sch ^ (r & 3);
            if (grow < rlimit)
                gl_lds16(gsrc + (size_t)grow * K + k0 + gch * 8, ldst + i * 512);
        }
        __syncthreads();

        bf16x8 ahf[4], alf[4], whf[4], wlf[4];
        #pragma unroll
        for (int r = 0; r < 4; ++r) {
            int rr = wrow * 64 + r * 16 + m;
            int off = rr * 32 + ((q ^ (rr & 3)) << 3);
            ahf[r] = *(const bf16x8*)(tAh + off);
            alf[r] = *(const bf16x8*)(tAl + off);
        }
        #pragma unroll
        for (int c = 0; c < 4; ++c) {
            int nn = wcol * 64 + c * 16 + m;
            int off = nn * 32 + ((q ^ (nn & 3)) << 3);
            whf[c] = *(const bf16x8*)(tWh + off);
            wlf[c] = *(const bf16x8*)(tWl + off);
        }
        #pragma unroll
        for (int r = 0; r < 4; ++r)
            #pragma unroll
            for (int c = 0; c < 4; ++c) {
                acc[r][c] = __builtin_amdgcn_mfma_f32_16x16x32_bf16(ahf[r], whf[c], acc[r][c], 0, 0, 0);
                acc[r][c] = __builtin_amdgcn_mfma_f32_16x16x32_bf16(ahf[r], wlf[c], acc[r][c], 0, 0, 0);
                acc[r][c] = __builtin_amdgcn_mfma_f32_16x16x32_bf16(alf[r], whf[c], acc[r][c], 0, 0, 0);
            }
        __syncthreads();
    }

    #pragma unroll
    for (int r = 0; r < 4; ++r) {
        int mrow = row0 + wrow * 64 + r * 16 + (lane >> 4) * 4;
        #pragma unroll
        for (int c = 0; c < 4; ++c) {
            int n = col0 + wcol * 64 + c * 16 + (lane & 15);
            float sc = bnscale[n];
            float sh = bnshift[n];
            f32x4 v = acc[r][c];
            if (fp16_out) {
                _Float16* base = X16 + (size_t)(n >> 5) * (N_NODES * 32) + (n & 31);
                #pragma unroll
                for (int g = 0; g < 4; ++g)
                    if (mrow + g < N_NODES)
                        base[(size_t)(mrow + g) * 32] =
                            (_Float16)fmaxf(fmaf(v[g], sc, sh), 0.f);
            } else {
                float* base = Xf + (size_t)(n >> 4) * (N_NODES * 16) + (n & 15);
                #pragma unroll
                for (int g = 0; g < 4; ++g)
                    if (mrow + g < N_NODES)
                        base[(size_t)(mrow + g) * 16] = fmaxf(fmaf(v[g], sc, sh), 0.f);
            }
        }
    }
}

// ---------------- BN prep (bias folded) ----------------
__global__ void k_bnprep(const float* __restrict__ gamma, const float* __restrict__ beta,
                         const float* __restrict__ mean, const float* __restrict__ var,
                         const float* __restrict__ bias,
                         float* __restrict__ scale, float* __restrict__ shift) {
    int l = blockIdx.x;
    int c = threadIdx.x;
    if (c < HID) {
        float s = gamma[l * HID + c] * rsqrtf(var[l * HID + c] + BN_EPS);
        scale[l * HID + c] = s;
        shift[l * HID + c] = beta[l * HID + c] + (bias[l * HID + c] - mean[l * HID + c]) * s;
    }
}

// ---------------- chunked gather on fp16 X: Âx -> bf16 hi/lo node-major ----------------
// fp16 chunk-major [nchunk][N][32]; one 3.2 MB slice per XCD; sorted slots;
// coalesced column-major edata. 4 thr/node, 8 ch/thread.
#define GNB 782  // ceil(50000/64) slot-blocks per chunk

__global__ __launch_bounds__(256) void k_gather(const _Float16* __restrict__ Xc,
                                                const int2* __restrict__ meta,
                                                const int2* __restrict__ edata,
                                                const int* __restrict__ perm,
                                                const float* __restrict__ selfn,
                                                ushort_t* __restrict__ Ah,
                                                ushort_t* __restrict__ Al,
                                                int K, int cshift) {
    int bid = blockIdx.x;
    int chunk = bid & ((1 << cshift) - 1);
    int nb = bid >> cshift;
    const _Float16* Hc = Xc + (size_t)chunk * (N_NODES * 32);
    int slot = nb * 64 + (threadIdx.x >> 2);
    if (slot >= N_NODES) return;
    int node = perm[slot];
    int2 m = meta[slot];
    int q8 = (threadIdx.x & 3) * 8;

    int stride = m.y & 0xFFFFF;
    int deg = m.y >> 20;
    const int2* ep = edata + m.x;
    float sn = selfn[node];

    float acc[8];
    {
        f16x8 hv = *(const f16x8*)(Hc + (size_t)node * 32 + q8);
        #pragma unroll
        for (int i = 0; i < 8; ++i) acc[i] = (float)hv[i] * sn;
    }
    int j = 0;
    for (; j + 3 < deg; j += 4) {
        int2 e0 = ep[(size_t)(j + 0) * stride];
        int2 e1 = ep[(size_t)(j + 1) * stride];
        int2 e2 = ep[(size_t)(j + 2) * stride];
        int2 e3 = ep[(size_t)(j + 3) * stride];
        f16x8 a0 = *(const f16x8*)(Hc + (size_t)e0.x * 32 + q8);
        f16x8 a1 = *(const f16x8*)(Hc + (size_t)e1.x * 32 + q8);
        f16x8 a2 = *(const f16x8*)(Hc + (size_t)e2.x * 32 + q8);
        f16x8 a3 = *(const f16x8*)(Hc + (size_t)e3.x * 32 + q8);
        float w0 = __int_as_float(e0.y);
        float w1 = __int_as_float(e1.y);
        float w2 = __int_as_float(e2.y);
        float w3 = __int_as_float(e3.y);
        #pragma unroll
        for (int i = 0; i < 8; ++i) {
            acc[i] = fmaf((float)a0[i], w0, acc[i]);
            acc[i] = fmaf((float)a1[i], w1, acc[i]);
            acc[i] = fmaf((float)a2[i], w2, acc[i]);
            acc[i] = fmaf((float)a3[i], w3, acc[i]);
        }
    }
    for (; j < deg; ++j) {
        int2 e0 = ep[(size_t)j * stride];
        f16x8 a0 = *(const f16x8*)(Hc + (size_t)e0.x * 32 + q8);
        float w0 = __int_as_float(e0.y);
        #pragma unroll
        for (int i = 0; i < 8; ++i) acc[i] = fmaf((float)a0[i], w0, acc[i]);
    }

    ushort_t hq[8], lq[8];
    #pragma unroll
    for (int i = 0; i < 8; ++i) {
        hq[i] = f2bf_rn(acc[i]);
        lq[i] = f2bf_rn(acc[i] - bf2f(hq[i]));
    }
    size_t ob = (size_t)node * K + chunk * 32 + q8;
    u32x4 hv4, lv4;
    hv4.x = ((unsigned int)hq[1] << 16) | hq[0];
    hv4.y = ((unsigned int)hq[3] << 16) | hq[2];
    hv4.z = ((unsigned int)hq[5] << 16) | hq[4];
    hv4.w = ((unsigned int)hq[7] << 16) | hq[6];
    lv4.x = ((unsigned int)lq[1] << 16) | lq[0];
    lv4.y = ((unsigned int)lq[3] << 16) | lq[2];
    lv4.z = ((unsigned int)lq[5] << 16) | lq[4];
    lv4.w = ((unsigned int)lq[7] << 16) | lq[6];
    __builtin_nontemporal_store(hv4, (u32x4*)(Ah + ob));
    __builtin_nontemporal_store(lv4, (u32x4*)(Al + ob));
}

// ---------------- segmented mean pool (X is fp32 chunk-major [16][N][16]) ----------------
#define POOL_SPAN 25
__global__ __launch_bounds__(256) void k_pool(const float* __restrict__ X,
                                              const int* __restrict__ batch,
                                              float* __restrict__ pooled,
                                              int* __restrict__ cnt, int N) {
    int n0 = blockIdx.x * POOL_SPAN;
    int c = threadIdx.x;
    const float* Xc = X + (size_t)(c >> 4) * (N_NODES * 16) + (c & 15);
    int nend = min(n0 + POOL_SPAN, N);
    float acc = 0.f;
    int curg = batch[n0];
    int segcnt = 0;
    for (int n = n0; n < nend; ++n) {
        int g = batch[n];
        if (g != curg) {
            atomicAdd(&pooled[(size_t)curg * HID + c], acc);
            if (c == 0) atomicAdd(&cnt[curg], segcnt);
            acc = 0.f;
            segcnt = 0;
            curg = g;
        }
        acc += Xc[(size_t)n * 16];
        ++segcnt;
    }
    atomicAdd(&pooled[(size_t)curg * HID + c], acc);
    if (c == 0) atomicAdd(&cnt[curg], segcnt);
}

// ---------------- MLP head ----------------
__global__ __launch_bounds__(128) void k_mlp(const float* __restrict__ pooled,
                                             const int* __restrict__ cnt,
                                             const float* __restrict__ W1,
                                             const float* __restrict__ b1,
                                             const float* __restrict__ W2,
                                             const float* __restrict__ b2,
                                             float* __restrict__ out) {
    __shared__ float prow[HID];
    __shared__ float hred[2];
    int g = blockIdx.x;
    int j = threadIdx.x;
    prow[j] = pooled[(size_t)g * HID + j];
    prow[j + 128] = pooled[(size_t)g * HID + 128 + j];
    __syncthreads();
    float acc = 0.f;
    #pragma unroll 8
    for (int k = 0; k < HID; ++k) acc += prow[k] * W1[k * 128 + j];
    float inv = 1.0f / fmaxf((float)cnt[g], 1.0f);
    float h = fmaxf(acc * inv + b1[j], 0.f);
    float p = h * W2[j];
    #pragma unroll
    for (int off = 32; off > 0; off >>= 1) p += __shfl_down(p, off, 64);
    if ((j & 63) == 0) hred[j >> 6] = p;
    __syncthreads();
    if (j == 0) out[g] = hred[0] + hred[1] + b2[0];
}

extern "C" void kernel_launch(void* const* d_in, const int* in_sizes, int n_in,
                              void* d_out, int out_size, void* d_ws, size_t ws_size,
                              hipStream_t stream) {
    const float* x      = (const float*)d_in[0];
    const int*   ei     = (const int*)d_in[1];
    const int*   batch  = (const int*)d_in[2];
    const float* convW0 = (const float*)d_in[3];
    const float* convWs = (const float*)d_in[4];
    const float* convB  = (const float*)d_in[5];
    const float* gamma  = (const float*)d_in[6];
    const float* beta   = (const float*)d_in[7];
    const float* mean   = (const float*)d_in[8];
    const float* var    = (const float*)d_in[9];
    const float* lin1W  = (const float*)d_in[10];
    const float* lin1b  = (const float*)d_in[11];
    const float* lin2W  = (const float*)d_in[12];
    const float* lin2b  = (const float*)d_in[13];
    float* out = (float*)d_out;

    const int* src = ei;
    const int* dst = ei + N_EDGES;

    const int WTOT = 128 * 256 + 3 * 256 * 256; // 229376

    float* ws = (float*)d_ws;
    float* xf32 = ws;                                    // N*HID fp32 chunk-major (final layer)
    _Float16* x16a = (_Float16*)(xf32 + (size_t)N_NODES * HID); // N*HID fp16 (ping)
    _Float16* x16b = x16a + (size_t)N_NODES * HID;       // N*HID fp16 (pong)
    ushort_t* Ahb = (ushort_t*)(x16b + (size_t)N_NODES * HID); // N*HID ushort
    ushort_t* Alb = Ahb + (size_t)N_NODES * HID;         // N*HID ushort
    ushort_t* WhT = Alb + (size_t)N_NODES * HID;         // WTOT
    ushort_t* WlT = WhT + WTOT;                          // WTOT
    float* dinv    = (float*)(WlT + WTOT);               // N
    float* selfn   = dinv + N_NODES;                     // N
    float* pooled  = selfn + N_NODES;                    // G*HID
    float* bnscale = pooled + (size_t)N_GRAPHS * HID;    // 4*HID
    float* bnshift = bnscale + N_LAYERS * HID;           // 4*HID
    int*   cnt     = (int*)(bnshift + N_LAYERS * HID);   // G
    int*   degi    = cnt + N_GRAPHS;                     // N
    int*   cursor  = degi + N_NODES;                     // N
    int*   perm    = cursor + N_NODES;                   // N
    int*   invperm = perm + N_NODES;                     // N
    int*   bins    = invperm + N_NODES;                  // NBIN
    int*   binstart= bins + NBIN;                        // NBIN
    int*   bincur  = binstart + NBIN;                    // NBIN
    int*   edgebase= bincur + NBIN;                      // NBIN
    int2*  meta    = (int2*)(edgebase + NBIN);           // N int2
    int2*  edata   = meta + N_NODES;                     // E int2

    hipMemsetAsync(degi, 0, (size_t)N_NODES * 4, stream);
    hipMemsetAsync(bins, 0, (size_t)NBIN * 4, stream);
    hipMemsetAsync(pooled, 0, (size_t)N_GRAPHS * HID * 4, stream);
    hipMemsetAsync(cnt, 0, (size_t)N_GRAPHS * 4, stream);

    // CSR build + norms + degree sort (all parallel; closed-form offsets)
    k_deg<<<(N_EDGES + 255) / 256, 256, 0, stream>>>(dst, degi, N_EDGES);
    k_nodenorm<<<(N_NODES + 255) / 256, 256, 0, stream>>>(degi, dinv, selfn, N_NODES);
    k_hist<<<(N_NODES + 255) / 256, 256, 0, stream>>>(degi, bins, N_NODES);
    k_binscan<<<1, 64, 0, stream>>>(bins, binstart, bincur, edgebase);
    k_assign<<<(N_NODES + 255) / 256, 256, 0, stream>>>(degi, binstart, edgebase, bins, bincur,
                                                        perm, invperm, meta, cursor, N_NODES);
    k_fill<<<(N_EDGES + 255) / 256, 256, 0, stream>>>(src, dst, dinv, invperm, meta, cursor,
                                                      edata, N_EDGES);

    // prep
    k_bnprep<<<N_LAYERS, 256, 0, stream>>>(gamma, beta, mean, var, convB, bnscale, bnshift);
    k_splitw<<<(WTOT + 255) / 256, 256, 0, stream>>>(convW0, convWs, WhT, WlT);
    k_tochunk<<<(N_NODES * IN_DIM / 4 + 255) / 256, 256, 0, stream>>>(x, x16a, N_NODES * IN_DIM / 4);

    // layers: gather (Âx, fp16 input) -> GEMM (+BN+ReLU epilogue)
    dim3 gg((N_NODES + 127) / 128, 2);
    _Float16* cur = x16a;
    for (int l = 0; l < N_LAYERS; ++l) {
        int K = (l == 0) ? IN_DIM : HID;
        int nchunk = K / 32;
        int cshift = (l == 0) ? 2 : 3;
        size_t woff = (l == 0) ? 0 : (size_t)(32768 + (l - 1) * 65536);
        k_gather<<<nchunk * GNB, 256, 0, stream>>>(cur, meta, edata, perm, selfn,
                                                   Ahb, Alb, K, cshift);
        _Float16* nxt = (cur == x16a) ? x16b : x16a;
        int fp16o = (l < N_LAYERS - 1) ? 1 : 0;
        k_gemm<<<gg, 256, 0, stream>>>(Ahb, Alb, WhT + woff, WlT + woff,
                                       bnscale + l * HID, bnshift + l * HID,
                                       xf32, nxt, K, fp16o);
        cur = nxt;
    }

    k_pool<<<(N_NODES + POOL_SPAN - 1) / POOL_SPAN, 256, 0, stream>>>(xf32, batch, pooled, cnt, N_NODES);
    k_mlp<<<N_GRAPHS, 128, 0, stream>>>(pooled, cnt, lin1W, lin1b, lin2W, lin2b, out);
}

// Round 18
// 531.816 us; speedup vs baseline: 1.5224x; 1.0887x over previous
//
#include <hip/hip_runtime.h>

#define N_NODES 50000
#define N_EDGES 800000
#define N_GRAPHS 2048
#define IN_DIM 128
#define HID 256
#define N_LAYERS 4
#define BN_EPS 1e-5f
#define NBIN 128
#define WSCALE 64.0f

typedef unsigned short ushort_t;
typedef float f32x4 __attribute__((ext_vector_type(4)));
typedef unsigned int u32x2 __attribute__((ext_vector_type(2)));
typedef unsigned int u32x4 __attribute__((ext_vector_type(4)));
typedef _Float16 f16x8 __attribute__((ext_vector_type(8)));
typedef _Float16 f16x4 __attribute__((ext_vector_type(4)));

// ---- async global->LDS, 16B per lane ----
__device__ __forceinline__ void gl_lds16(const ushort_t* g, ushort_t* l) {
    __builtin_amdgcn_global_load_lds(
        (const __attribute__((address_space(1))) void*)g,
        (__attribute__((address_space(3))) void*)l, 16, 0, 0);
}

// ---------------- degree count ----------------
__global__ void k_deg(const int* __restrict__ dst, int* __restrict__ degi, int E) {
    int e = blockIdx.x * blockDim.x + threadIdx.x;
    if (e < E) atomicAdd(&degi[dst[e]], 1);
}

__global__ void k_nodenorm(const int* __restrict__ degi, float* __restrict__ dinv,
                           float* __restrict__ selfn, int N) {
    int n = blockIdx.x * blockDim.x + threadIdx.x;
    if (n < N) {
        float d = 1.0f + (float)degi[n];
        dinv[n] = 1.0f / sqrtf(d);
        selfn[n] = 1.0f / d;
    }
}

// ---------------- degree histogram (hierarchical) ----------------
__global__ __launch_bounds__(256) void k_hist(const int* __restrict__ degi,
                                              int* __restrict__ bins, int N) {
    __shared__ int lbin[NBIN];
    int t = threadIdx.x;
    if (t < NBIN) lbin[t] = 0;
    __syncthreads();
    int n = blockIdx.x * 256 + t;
    if (n < N) atomicAdd(&lbin[min(degi[n], NBIN - 1)], 1);
    __syncthreads();
    if (t < NBIN && lbin[t] > 0) atomicAdd(&bins[t], lbin[t]);
}

// ---------------- bin prefix (tiny serial, 128 iters) ----------------
__global__ void k_binscan(const int* __restrict__ bins, int* __restrict__ binstart,
                          int* __restrict__ bincur, int* __restrict__ edgebase) {
    if (threadIdx.x == 0) {
        int run = 0, erun = 0;
        for (int d = 0; d < NBIN; ++d) {
            binstart[d] = run;
            bincur[d] = run;
            edgebase[d] = erun;
            run += bins[d];
            erun += bins[d] * d;
        }
    }
}

// ---------------- parallel slot assignment, hierarchical; emits per-slot meta ----------------
__global__ __launch_bounds__(256) void k_assign(const int* __restrict__ degi,
                                                const int* __restrict__ binstart,
                                                const int* __restrict__ edgebase,
                                                const int* __restrict__ bins,
                                                int* __restrict__ bincur,
                                                int* __restrict__ perm, int* __restrict__ invperm,
                                                int2* __restrict__ meta, int* __restrict__ cursor,
                                                int N) {
    __shared__ int lbin[NBIN];
    __shared__ int lbase[NBIN];
    int t = threadIdx.x;
    if (t < NBIN) lbin[t] = 0;
    __syncthreads();
    int n = blockIdx.x * 256 + t;
    int d = 0, lrank = 0;
    if (n < N) {
        d = min(degi[n], NBIN - 1);
        lrank = atomicAdd(&lbin[d], 1);
    }
    __syncthreads();
    if (t < NBIN && lbin[t] > 0) lbase[t] = atomicAdd(&bincur[t], lbin[t]);
    __syncthreads();
    if (n < N) {
        int slot = lbase[d] + lrank;
        perm[slot] = n;
        invperm[n] = slot;
        int2 m;
        m.x = edgebase[d] + (slot - binstart[d]);
        m.y = bins[d] | (d << 20);
        meta[slot] = m;
        cursor[slot] = 0;
    }
}

// ---------------- CSR fill into bin-interleaved layout ----------------
__global__ void k_fill(const int* __restrict__ src, const int* __restrict__ dst,
                       const float* __restrict__ dinv, const int* __restrict__ invperm,
                       const int2* __restrict__ meta, int* __restrict__ cursor,
                       int2* __restrict__ edata, int E) {
    int e = blockIdx.x * blockDim.x + threadIdx.x;
    if (e >= E) return;
    int s = src[e], d = dst[e];
    int slot = invperm[d];
    int2 m = meta[slot];
    int j = atomicAdd(&cursor[slot], 1);
    int pos = m.x + j * (m.y & 0xFFFFF);
    int2 v;
    v.x = s;
    v.y = __float_as_int(dinv[s] * dinv[d]);
    edata[pos] = v;
}

// ---------------- x (node-major [N][128] fp32) -> fp16 chunk-major [4][N][32] ----------------
__global__ __launch_bounds__(256) void k_tochunk(const float* __restrict__ x,
                                                 _Float16* __restrict__ X16, int total4) {
    int i = blockIdx.x * blockDim.x + threadIdx.x;
    if (i >= total4) return;
    float4 v = ((const float4*)x)[i];
    int n = i >> 5;
    int c0 = (i & 31) * 4;
    f16x4 o;
    o.x = (_Float16)v.x; o.y = (_Float16)v.y; o.z = (_Float16)v.z; o.w = (_Float16)v.w;
    *(f16x4*)(X16 + (size_t)(c0 >> 5) * (N_NODES * 32) + (size_t)n * 32 + (c0 & 31)) = o;
}

// ---------------- split + transpose weights -> fp16 hi/lo, PRESCALED x64 ----------------
// Wl stays in fp16 normal range (|Wl| ~ 64*sigma*2^-12 ~ 1e-3 >> 6.1e-5).
__global__ void k_splitw(const float* __restrict__ W0, const float* __restrict__ Ws,
                         _Float16* __restrict__ Wh, _Float16* __restrict__ Wl) {
    int i = blockIdx.x * blockDim.x + threadIdx.x;
    const int total = 128 * 256 + 3 * 256 * 256;
    if (i >= total) return;
    float v;
    if (i < 32768) {
        int n = i >> 7, k = i & 127;
        v = W0[k * 256 + n];
    } else {
        int t = i - 32768;
        int l = t >> 16;
        int r = t & 65535;
        int n = r >> 8, k = r & 255;
        v = Ws[l * 65536 + k * 256 + n];
    }
    v *= WSCALE;
    _Float16 h = (_Float16)v;
    Wh[i] = h;
    Wl[i] = (_Float16)(v - (float)h);
}

// ---------------- MFMA fp16 2-term GEMM + fused BN/ReLU epilogue ----------------
// A fp16 node-major [N][K]; W fp16 hi/lo node-major [256][K], prescaled x64
// (1/64 folded into bnscale). acc = A*Wh + A*Wl. 3 LDS tiles (24 KB), no Al tile.
__global__ __launch_bounds__(256) void k_gemm(const _Float16* __restrict__ A,
                                              const _Float16* __restrict__ Wh,
                                              const _Float16* __restrict__ Wl,
                                              const float* __restrict__ bnscale,
                                              const float* __restrict__ bnshift,
                                              float* __restrict__ Xf,
                                              _Float16* __restrict__ X16,
                                              int K, int fp16_out) {
    __shared__ _Float16 sm[3 * 128 * 32]; // 24 KB: A | Wh | Wl tiles
    _Float16* tA  = sm;
    _Float16* tWh = sm + 4096;
    _Float16* tWl = sm + 8192;

    int tid = threadIdx.x;
    int lane = tid & 63;
    int w = tid >> 6;
    int wrow = w & 1, wcol = w >> 1;
    int row0 = blockIdx.x * 128;
    int col0 = blockIdx.y * 128;

    // staging roles: w0 -> A rows, w1 -> Wh cols, w2 -> Wl cols, w3 idle
    const _Float16* gsrc = (w == 0) ? A : (w == 1) ? Wh : Wl;
    int rbase = (w == 0) ? row0 : col0;
    int rlimit = (w == 0) ? N_NODES : (col0 + 128);
    _Float16* ldst = sm + w * 4096;
    int srow = lane >> 2;
    int sch = lane & 3;

    f32x4 acc[4][4] = {};
    int m = lane & 15, q = lane >> 4;

    for (int k0 = 0; k0 < K; k0 += 32) {
        if (w < 3) {
            #pragma unroll
            for (int i = 0; i < 8; ++i) {
                int r = i * 16 + srow;
                int grow = rbase + r;
                int gch = sch ^ (r & 3);
                if (grow < rlimit)
                    gl_lds16((const ushort_t*)(gsrc + (size_t)grow * K + k0 + gch * 8),
                             (ushort_t*)(ldst + i * 512));
            }
        }
        __syncthreads();

        f16x8 af[4], whf[4], wlf[4];
        #pragma unroll
        for (int r = 0; r < 4; ++r) {
            int rr = wrow * 64 + r * 16 + m;
            int off = rr * 32 + ((q ^ (rr & 3)) << 3);
            af[r] = *(const f16x8*)(tA + off);
        }
        #pragma unroll
        for (int c = 0; c < 4; ++c) {
            int nn = wcol * 64 + c * 16 + m;
            int off = nn * 32 + ((q ^ (nn & 3)) << 3);
            whf[c] = *(const f16x8*)(tWh + off);
            wlf[c] = *(const f16x8*)(tWl + off);
        }
        #pragma unroll
        for (int r = 0; r < 4; ++r)
            #pragma unroll
            for (int c = 0; c < 4; ++c) {
                acc[r][c] = __builtin_amdgcn_mfma_f32_16x16x32_f16(af[r], whf[c], acc[r][c], 0, 0, 0);
                acc[r][c] = __builtin_amdgcn_mfma_f32_16x16x32_f16(af[r], wlf[c], acc[r][c], 0, 0, 0);
            }
        __syncthreads();
    }

    #pragma unroll
    for (int r = 0; r < 4; ++r) {
        int mrow = row0 + wrow * 64 + r * 16 + (lane >> 4) * 4;
        #pragma unroll
        for (int c = 0; c < 4; ++c) {
            int n = col0 + wcol * 64 + c * 16 + (lane & 15);
            float sc = bnscale[n];
            float sh = bnshift[n];
            f32x4 v = acc[r][c];
            if (fp16_out) {
                _Float16* base = X16 + (size_t)(n >> 5) * (N_NODES * 32) + (n & 31);
                #pragma unroll
                for (int g = 0; g < 4; ++g)
                    if (mrow + g < N_NODES)
                        base[(size_t)(mrow + g) * 32] =
                            (_Float16)fmaxf(fmaf(v[g], sc, sh), 0.f);
            } else {
                float* base = Xf + (size_t)(n >> 4) * (N_NODES * 16) + (n & 15);
                #pragma unroll
                for (int g = 0; g < 4; ++g)
                    if (mrow + g < N_NODES)
                        base[(size_t)(mrow + g) * 16] = fmaxf(fmaf(v[g], sc, sh), 0.f);
            }
        }
    }
}

// ---------------- BN prep (bias folded; 1/WSCALE folded into scale) ----------------
__global__ void k_bnprep(const float* __restrict__ gamma, const float* __restrict__ beta,
                         const float* __restrict__ mean, const float* __restrict__ var,
                         const float* __restrict__ bias,
                         float* __restrict__ scale, float* __restrict__ shift) {
    int l = blockIdx.x;
    int c = threadIdx.x;
    if (c < HID) {
        float s = gamma[l * HID + c] * rsqrtf(var[l * HID + c] + BN_EPS);
        scale[l * HID + c] = s / WSCALE;
        shift[l * HID + c] = beta[l * HID + c] + (bias[l * HID + c] - mean[l * HID + c]) * s;
    }
}

// ---------------- chunked gather on fp16 X: Âx -> fp16 A node-major ----------------
// fp16 chunk-major [nchunk][N][32]; one 3.2 MB slice per XCD; sorted slots;
// coalesced column-major edata. 4 thr/node, 8 ch/thread.
#define GNB 782  // ceil(50000/64) slot-blocks per chunk

__global__ __launch_bounds__(256) void k_gather(const _Float16* __restrict__ Xc,
                                                const int2* __restrict__ meta,
                                                const int2* __restrict__ edata,
                                                const int* __restrict__ perm,
                                                const float* __restrict__ selfn,
                                                _Float16* __restrict__ A,
                                                int K, int cshift) {
    int bid = blockIdx.x;
    int chunk = bid & ((1 << cshift) - 1);
    int nb = bid >> cshift;
    const _Float16* Hc = Xc + (size_t)chunk * (N_NODES * 32);
    int slot = nb * 64 + (threadIdx.x >> 2);
    if (slot >= N_NODES) return;
    int node = perm[slot];
    int2 m = meta[slot];
    int q8 = (threadIdx.x & 3) * 8;

    int stride = m.y & 0xFFFFF;
    int deg = m.y >> 20;
    const int2* ep = edata + m.x;
    float sn = selfn[node];

    float acc[8];
    {
        f16x8 hv = *(const f16x8*)(Hc + (size_t)node * 32 + q8);
        #pragma unroll
        for (int i = 0; i < 8; ++i) acc[i] = (float)hv[i] * sn;
    }
    int j = 0;
    for (; j + 3 < deg; j += 4) {
        int2 e0 = ep[(size_t)(j + 0) * stride];
        int2 e1 = ep[(size_t)(j + 1) * stride];
        int2 e2 = ep[(size_t)(j + 2) * stride];
        int2 e3 = ep[(size_t)(j + 3) * stride];
        f16x8 a0 = *(const f16x8*)(Hc + (size_t)e0.x * 32 + q8);
        f16x8 a1 = *(const f16x8*)(Hc + (size_t)e1.x * 32 + q8);
        f16x8 a2 = *(const f16x8*)(Hc + (size_t)e2.x * 32 + q8);
        f16x8 a3 = *(const f16x8*)(Hc + (size_t)e3.x * 32 + q8);
        float w0 = __int_as_float(e0.y);
        float w1 = __int_as_float(e1.y);
        float w2 = __int_as_float(e2.y);
        float w3 = __int_as_float(e3.y);
        #pragma unroll
        for (int i = 0; i < 8; ++i) {
            acc[i] = fmaf((float)a0[i], w0, acc[i]);
            acc[i] = fmaf((float)a1[i], w1, acc[i]);
            acc[i] = fmaf((float)a2[i], w2, acc[i]);
            acc[i] = fmaf((float)a3[i], w3, acc[i]);
        }
    }
    for (; j < deg; ++j) {
        int2 e0 = ep[(size_t)j * stride];
        f16x8 a0 = *(const f16x8*)(Hc + (size_t)e0.x * 32 + q8);
        float w0 = __int_as_float(e0.y);
        #pragma unroll
        for (int i = 0; i < 8; ++i) acc[i] = fmaf((float)a0[i], w0, acc[i]);
    }

    f16x8 o;
    #pragma unroll
    for (int i = 0; i < 8; ++i) o[i] = (_Float16)acc[i];
    u32x4 uv = *(u32x4*)&o;
    __builtin_nontemporal_store(uv, (u32x4*)(A + (size_t)node * K + chunk * 32 + q8));
}

// ---------------- segmented mean pool (X is fp32 chunk-major [16][N][16]) ----------------
#define POOL_SPAN 25
__global__ __launch_bounds__(256) void k_pool(const float* __restrict__ X,
                                              const int* __restrict__ batch,
                                              float* __restrict__ pooled,
                                              int* __restrict__ cnt, int N) {
    int n0 = blockIdx.x * POOL_SPAN;
    int c = threadIdx.x;
    const float* Xc = X + (size_t)(c >> 4) * (N_NODES * 16) + (c & 15);
    int nend = min(n0 + POOL_SPAN, N);
    float acc = 0.f;
    int curg = batch[n0];
    int segcnt = 0;
    for (int n = n0; n < nend; ++n) {
        int g = batch[n];
        if (g != curg) {
            atomicAdd(&pooled[(size_t)curg * HID + c], acc);
            if (c == 0) atomicAdd(&cnt[curg], segcnt);
            acc = 0.f;
            segcnt = 0;
            curg = g;
        }
        acc += Xc[(size_t)n * 16];
        ++segcnt;
    }
    atomicAdd(&pooled[(size_t)curg * HID + c], acc);
    if (c == 0) atomicAdd(&cnt[curg], segcnt);
}

// ---------------- MLP head ----------------
__global__ __launch_bounds__(128) void k_mlp(const float* __restrict__ pooled,
                                             const int* __restrict__ cnt,
                                             const float* __restrict__ W1,
                                             const float* __restrict__ b1,
                                             const float* __restrict__ W2,
                                             const float* __restrict__ b2,
                                             float* __restrict__ out) {
    __shared__ float prow[HID];
    __shared__ float hred[2];
    int g = blockIdx.x;
    int j = threadIdx.x;
    prow[j] = pooled[(size_t)g * HID + j];
    prow[j + 128] = pooled[(size_t)g * HID + 128 + j];
    __syncthreads();
    float acc = 0.f;
    #pragma unroll 8
    for (int k = 0; k < HID; ++k) acc += prow[k] * W1[k * 128 + j];
    float inv = 1.0f / fmaxf((float)cnt[g], 1.0f);
    float h = fmaxf(acc * inv + b1[j], 0.f);
    float p = h * W2[j];
    #pragma unroll
    for (int off = 32; off > 0; off >>= 1) p += __shfl_down(p, off, 64);
    if ((j & 63) == 0) hred[j >> 6] = p;
    __syncthreads();
    if (j == 0) out[g] = hred[0] + hred[1] + b2[0];
}

extern "C" void kernel_launch(void* const* d_in, const int* in_sizes, int n_in,
                              void* d_out, int out_size, void* d_ws, size_t ws_size,
                              hipStream_t stream) {
    const float* x      = (const float*)d_in[0];
    const int*   ei     = (const int*)d_in[1];
    const int*   batch  = (const int*)d_in[2];
    const float* convW0 = (const float*)d_in[3];
    const float* convWs = (const float*)d_in[4];
    const float* convB  = (const float*)d_in[5];
    const float* gamma  = (const float*)d_in[6];
    const float* beta   = (const float*)d_in[7];
    const float* mean   = (const float*)d_in[8];
    const float* var    = (const float*)d_in[9];
    const float* lin1W  = (const float*)d_in[10];
    const float* lin1b  = (const float*)d_in[11];
    const float* lin2W  = (const float*)d_in[12];
    const float* lin2b  = (const float*)d_in[13];
    float* out = (float*)d_out;

    const int* src = ei;
    const int* dst = ei + N_EDGES;

    const int WTOT = 128 * 256 + 3 * 256 * 256; // 229376

    float* ws = (float*)d_ws;
    float* xf32 = ws;                                    // N*HID fp32 chunk-major (final layer)
    _Float16* x16a = (_Float16*)(xf32 + (size_t)N_NODES * HID); // N*HID fp16 (ping)
    _Float16* x16b = x16a + (size_t)N_NODES * HID;       // N*HID fp16 (pong)
    _Float16* Ab   = x16b + (size_t)N_NODES * HID;       // N*HID fp16 (GEMM A operand)
    _Float16* Wh16 = Ab + (size_t)N_NODES * HID;         // WTOT fp16
    _Float16* Wl16 = Wh16 + WTOT;                        // WTOT fp16
    float* dinv    = (float*)(Wl16 + WTOT);              // N
    float* selfn   = dinv + N_NODES;                     // N
    float* pooled  = selfn + N_NODES;                    // G*HID
    float* bnscale = pooled + (size_t)N_GRAPHS * HID;    // 4*HID
    float* bnshift = bnscale + N_LAYERS * HID;           // 4*HID
    int*   cnt     = (int*)(bnshift + N_LAYERS * HID);   // G
    int*   degi    = cnt + N_GRAPHS;                     // N
    int*   cursor  = degi + N_NODES;                     // N
    int*   perm    = cursor + N_NODES;                   // N
    int*   invperm = perm + N_NODES;                     // N
    int*   bins    = invperm + N_NODES;                  // NBIN
    int*   binstart= bins + NBIN;                        // NBIN
    int*   bincur  = binstart + NBIN;                    // NBIN
    int*   edgebase= bincur + NBIN;                      // NBIN
    int2*  meta    = (int2*)(edgebase + NBIN);           // N int2
    int2*  edata   = meta + N_NODES;                     // E int2

    hipMemsetAsync(degi, 0, (size_t)N_NODES * 4, stream);
    hipMemsetAsync(bins, 0, (size_t)NBIN * 4, stream);
    hipMemsetAsync(pooled, 0, (size_t)N_GRAPHS * HID * 4, stream);
    hipMemsetAsync(cnt, 0, (size_t)N_GRAPHS * 4, stream);

    // CSR build + norms + degree sort (all parallel; closed-form offsets)
    k_deg<<<(N_EDGES + 255) / 256, 256, 0, stream>>>(dst, degi, N_EDGES);
    k_nodenorm<<<(N_NODES + 255) / 256, 256, 0, stream>>>(degi, dinv, selfn, N_NODES);
    k_hist<<<(N_NODES + 255) / 256, 256, 0, stream>>>(degi, bins, N_NODES);
    k_binscan<<<1, 64, 0, stream>>>(bins, binstart, bincur, edgebase);
    k_assign<<<(N_NODES + 255) / 256, 256, 0, stream>>>(degi, binstart, edgebase, bins, bincur,
                                                        perm, invperm, meta, cursor, N_NODES);
    k_fill<<<(N_EDGES + 255) / 256, 256, 0, stream>>>(src, dst, dinv, invperm, meta, cursor,
                                                      edata, N_EDGES);

    // prep
    k_bnprep<<<N_LAYERS, 256, 0, stream>>>(gamma, beta, mean, var, convB, bnscale, bnshift);
    k_splitw<<<(WTOT + 255) / 256, 256, 0, stream>>>(convW0, convWs, Wh16, Wl16);
    k_tochunk<<<(N_NODES * IN_DIM / 4 + 255) / 256, 256, 0, stream>>>(x, x16a, N_NODES * IN_DIM / 4);

    // layers: gather (Âx, fp16) -> fp16 2-term GEMM (+BN+ReLU epilogue)
    dim3 gg((N_NODES + 127) / 128, 2);
    _Float16* cur = x16a;
    for (int l = 0; l < N_LAYERS; ++l) {
        int K = (l == 0) ? IN_DIM : HID;
        int nchunk = K / 32;
        int cshift = (l == 0) ? 2 : 3;
        size_t woff = (l == 0) ? 0 : (size_t)(32768 + (l - 1) * 65536);
        k_gather<<<nchunk * GNB, 256, 0, stream>>>(cur, meta, edata, perm, selfn,
                                                   Ab, K, cshift);
        _Float16* nxt = (cur == x16a) ? x16b : x16a;
        int fp16o = (l < N_LAYERS - 1) ? 1 : 0;
        k_gemm<<<gg, 256, 0, stream>>>(Ab, Wh16 + woff, Wl16 + woff,
                                       bnscale + l * HID, bnshift + l * HID,
                                       xf32, nxt, K, fp16o);
        cur = nxt;
    }

    k_pool<<<(N_NODES + POOL_SPAN - 1) / POOL_SPAN, 256, 0, stream>>>(xf32, batch, pooled, cnt, N_NODES);
    k_mlp<<<N_GRAPHS, 128, 0, stream>>>(pooled, cnt, lin1W, lin1b, lin2W, lin2b, out);
}

// Round 19
// 508.458 us; speedup vs baseline: 1.5923x; 1.0459x over previous
//
#include <hip/hip_runtime.h>

#define N_NODES 50000
#define N_EDGES 800000
#define N_GRAPHS 2048
#define IN_DIM 128
#define HID 256
#define N_LAYERS 4
#define BN_EPS 1e-5f
#define NBIN 128
#define WSCALE 64.0f

typedef unsigned short ushort_t;
typedef float f32x4 __attribute__((ext_vector_type(4)));
typedef unsigned int u32x4 __attribute__((ext_vector_type(4)));
typedef _Float16 f16x8 __attribute__((ext_vector_type(8)));
typedef _Float16 f16x4 __attribute__((ext_vector_type(4)));

// ---- async global->LDS, 16B per lane ----
__device__ __forceinline__ void gl_lds16(const ushort_t* g, ushort_t* l) {
    __builtin_amdgcn_global_load_lds(
        (const __attribute__((address_space(1))) void*)g,
        (__attribute__((address_space(3))) void*)l, 16, 0, 0);
}

// ---------------- degree count ----------------
__global__ void k_deg(const int* __restrict__ dst, int* __restrict__ degi, int E) {
    int e = blockIdx.x * blockDim.x + threadIdx.x;
    if (e < E) atomicAdd(&degi[dst[e]], 1);
}

// ---------------- node norms + degree histogram (fused, hierarchical) ----------------
__global__ __launch_bounds__(256) void k_nodeprep(const int* __restrict__ degi,
                                                  float* __restrict__ dinv,
                                                  float* __restrict__ selfn,
                                                  int* __restrict__ bins, int N) {
    __shared__ int lbin[NBIN];
    int t = threadIdx.x;
    if (t < NBIN) lbin[t] = 0;
    __syncthreads();
    int n = blockIdx.x * 256 + t;
    if (n < N) {
        int dg = degi[n];
        float d = 1.0f + (float)dg;
        dinv[n] = 1.0f / sqrtf(d);
        selfn[n] = 1.0f / d;
        atomicAdd(&lbin[min(dg, NBIN - 1)], 1);
    }
    __syncthreads();
    if (t < NBIN && lbin[t] > 0) atomicAdd(&bins[t], lbin[t]);
}

// ---------------- bin prefix (tiny serial, 128 iters) ----------------
__global__ void k_binscan(const int* __restrict__ bins, int* __restrict__ binstart,
                          int* __restrict__ bincur, int* __restrict__ edgebase) {
    if (threadIdx.x == 0) {
        int run = 0, erun = 0;
        for (int d = 0; d < NBIN; ++d) {
            binstart[d] = run;
            bincur[d] = run;
            edgebase[d] = erun;
            run += bins[d];
            erun += bins[d] * d;
        }
    }
}

// ---------------- parallel slot assignment, hierarchical; emits per-slot meta ----------------
__global__ __launch_bounds__(256) void k_assign(const int* __restrict__ degi,
                                                const int* __restrict__ binstart,
                                                const int* __restrict__ edgebase,
                                                const int* __restrict__ bins,
                                                int* __restrict__ bincur,
                                                int* __restrict__ perm, int* __restrict__ invperm,
                                                int2* __restrict__ meta, int* __restrict__ cursor,
                                                int N) {
    __shared__ int lbin[NBIN];
    __shared__ int lbase[NBIN];
    int t = threadIdx.x;
    if (t < NBIN) lbin[t] = 0;
    __syncthreads();
    int n = blockIdx.x * 256 + t;
    int d = 0, lrank = 0;
    if (n < N) {
        d = min(degi[n], NBIN - 1);
        lrank = atomicAdd(&lbin[d], 1);
    }
    __syncthreads();
    if (t < NBIN && lbin[t] > 0) lbase[t] = atomicAdd(&bincur[t], lbin[t]);
    __syncthreads();
    if (n < N) {
        int slot = lbase[d] + lrank;
        perm[slot] = n;
        invperm[n] = slot;
        int2 m;
        m.x = edgebase[d] + (slot - binstart[d]);
        m.y = bins[d] | (d << 20);
        meta[slot] = m;
        cursor[slot] = 0;
    }
}

// ---------------- CSR fill into bin-interleaved layout ----------------
__global__ void k_fill(const int* __restrict__ src, const int* __restrict__ dst,
                       const float* __restrict__ dinv, const int* __restrict__ invperm,
                       const int2* __restrict__ meta, int* __restrict__ cursor,
                       int2* __restrict__ edata, int E) {
    int e = blockIdx.x * blockDim.x + threadIdx.x;
    if (e >= E) return;
    int s = src[e], d = dst[e];
    int slot = invperm[d];
    int2 m = meta[slot];
    int j = atomicAdd(&cursor[slot], 1);
    int pos = m.x + j * (m.y & 0xFFFFF);
    int2 v;
    v.x = s;
    v.y = __float_as_int(dinv[s] * dinv[d]);
    edata[pos] = v;
}

// ---------------- graph boundaries from sorted batch ----------------
__global__ void k_bounds(const int* __restrict__ batch, int* __restrict__ gstart,
                         int* __restrict__ gend, int N) {
    int n = blockIdx.x * blockDim.x + threadIdx.x;
    if (n >= N) return;
    int g = batch[n];
    if (n == 0 || batch[n - 1] != g) gstart[g] = n;
    if (n == N - 1 || batch[n + 1] != g) gend[g] = n + 1;
}

// ---------------- fused prep: bnprep | splitw | tochunk (range-dispatched) ----------------
__global__ __launch_bounds__(256) void k_prep(const float* __restrict__ gamma,
                                              const float* __restrict__ beta,
                                              const float* __restrict__ mean,
                                              const float* __restrict__ var,
                                              const float* __restrict__ bias,
                                              const float* __restrict__ W0,
                                              const float* __restrict__ Ws,
                                              const float* __restrict__ x,
                                              float* __restrict__ scale,
                                              float* __restrict__ shift,
                                              _Float16* __restrict__ Wh,
                                              _Float16* __restrict__ Wl,
                                              _Float16* __restrict__ X16) {
    int id = blockIdx.x * 256 + threadIdx.x;
    if (id < N_LAYERS * HID) {
        float s = gamma[id] * rsqrtf(var[id] + BN_EPS);
        scale[id] = s / WSCALE;
        shift[id] = beta[id] + (bias[id] - mean[id]) * s;
        return;
    }
    id -= N_LAYERS * HID;
    const int WT = 128 * 256 + 3 * 256 * 256;
    if (id < WT) {
        float v;
        if (id < 32768) {
            int n = id >> 7, k = id & 127;
            v = W0[k * 256 + n];
        } else {
            int t = id - 32768;
            int l = t >> 16;
            int r = t & 65535;
            int n = r >> 8, k = r & 255;
            v = Ws[l * 65536 + k * 256 + n];
        }
        v *= WSCALE;
        _Float16 h = (_Float16)v;
        Wh[id] = h;
        Wl[id] = (_Float16)(v - (float)h);
        return;
    }
    id -= WT;
    const int total4 = N_NODES * IN_DIM / 4;
    if (id < total4) {
        float4 v = ((const float4*)x)[id];
        int n = id >> 5;
        int c0 = (id & 31) * 4;
        f16x4 o;
        o.x = (_Float16)v.x; o.y = (_Float16)v.y; o.z = (_Float16)v.z; o.w = (_Float16)v.w;
        *(f16x4*)(X16 + (size_t)(c0 >> 5) * (N_NODES * 32) + (size_t)n * 32 + (c0 & 31)) = o;
    }
}

// ---------------- MFMA fp16 2-term GEMM + fused BN/ReLU epilogue (fp16 out) ----------------
// A fp16 node-major [N][K]; W fp16 hi/lo node-major [256][K], prescaled x64
// (1/64 folded into bnscale). Output fp16 chunk-major [8][N][32].
__global__ __launch_bounds__(256) void k_gemm(const _Float16* __restrict__ A,
                                              const _Float16* __restrict__ Wh,
                                              const _Float16* __restrict__ Wl,
                                              const float* __restrict__ bnscale,
                                              const float* __restrict__ bnshift,
                                              _Float16* __restrict__ X16, int K) {
    __shared__ _Float16 sm[3 * 128 * 32]; // 24 KB: A | Wh | Wl tiles
    _Float16* tA  = sm;
    _Float16* tWh = sm + 4096;
    _Float16* tWl = sm + 8192;

    int tid = threadIdx.x;
    int lane = tid & 63;
    int w = tid >> 6;
    int wrow = w & 1, wcol = w >> 1;
    int row0 = blockIdx.x * 128;
    int col0 = blockIdx.y * 128;

    const _Float16* gsrc = (w == 0) ? A : (w == 1) ? Wh : Wl;
    int rbase = (w == 0) ? row0 : col0;
    int rlimit = (w == 0) ? N_NODES : (col0 + 128);
    _Float16* ldst = sm + w * 4096;
    int srow = lane >> 2;
    int sch = lane & 3;

    f32x4 acc[4][4] = {};
    int m = lane & 15, q = lane >> 4;

    for (int k0 = 0; k0 < K; k0 += 32) {
        if (w < 3) {
            #pragma unroll
            for (int i = 0; i < 8; ++i) {
                int r = i * 16 + srow;
                int grow = rbase + r;
                int gch = sch ^ (r & 3);
                if (grow < rlimit)
                    gl_lds16((const ushort_t*)(gsrc + (size_t)grow * K + k0 + gch * 8),
                             (ushort_t*)(ldst + i * 512));
            }
        }
        __syncthreads();

        f16x8 af[4], whf[4], wlf[4];
        #pragma unroll
        for (int r = 0; r < 4; ++r) {
            int rr = wrow * 64 + r * 16 + m;
            int off = rr * 32 + ((q ^ (rr & 3)) << 3);
            af[r] = *(const f16x8*)(tA + off);
        }
        #pragma unroll
        for (int c = 0; c < 4; ++c) {
            int nn = wcol * 64 + c * 16 + m;
            int off = nn * 32 + ((q ^ (nn & 3)) << 3);
            whf[c] = *(const f16x8*)(tWh + off);
            wlf[c] = *(const f16x8*)(tWl + off);
        }
        #pragma unroll
        for (int r = 0; r < 4; ++r)
            #pragma unroll
            for (int c = 0; c < 4; ++c) {
                acc[r][c] = __builtin_amdgcn_mfma_f32_16x16x32_f16(af[r], whf[c], acc[r][c], 0, 0, 0);
                acc[r][c] = __builtin_amdgcn_mfma_f32_16x16x32_f16(af[r], wlf[c], acc[r][c], 0, 0, 0);
            }
        __syncthreads();
    }

    #pragma unroll
    for (int r = 0; r < 4; ++r) {
        int mrow = row0 + wrow * 64 + r * 16 + (lane >> 4) * 4;
        #pragma unroll
        for (int c = 0; c < 4; ++c) {
            int n = col0 + wcol * 64 + c * 16 + (lane & 15);
            float sc = bnscale[n];
            float sh = bnshift[n];
            f32x4 v = acc[r][c];
            _Float16* base = X16 + (size_t)(n >> 5) * (N_NODES * 32) + (n & 31);
            #pragma unroll
            for (int g = 0; g < 4; ++g)
                if (mrow + g < N_NODES)
                    base[(size_t)(mrow + g) * 32] =
                        (_Float16)fmaxf(fmaf(v[g], sc, sh), 0.f);
        }
    }
}

// ---------------- chunked gather on fp16 X: Âx -> fp16 A node-major ----------------
#define GNB 782  // ceil(50000/64) slot-blocks per chunk

__global__ __launch_bounds__(256) void k_gather(const _Float16* __restrict__ Xc,
                                                const int2* __restrict__ meta,
                                                const int2* __restrict__ edata,
                                                const int* __restrict__ perm,
                                                const float* __restrict__ selfn,
                                                _Float16* __restrict__ A,
                                                int K, int cshift) {
    int bid = blockIdx.x;
    int chunk = bid & ((1 << cshift) - 1);
    int nb = bid >> cshift;
    const _Float16* Hc = Xc + (size_t)chunk * (N_NODES * 32);
    int slot = nb * 64 + (threadIdx.x >> 2);
    if (slot >= N_NODES) return;
    int node = perm[slot];
    int2 m = meta[slot];
    int q8 = (threadIdx.x & 3) * 8;

    int stride = m.y & 0xFFFFF;
    int deg = m.y >> 20;
    const int2* ep = edata + m.x;
    float sn = selfn[node];

    float acc[8];
    {
        f16x8 hv = *(const f16x8*)(Hc + (size_t)node * 32 + q8);
        #pragma unroll
        for (int i = 0; i < 8; ++i) acc[i] = (float)hv[i] * sn;
    }
    int j = 0;
    for (; j + 3 < deg; j += 4) {
        int2 e0 = ep[(size_t)(j + 0) * stride];
        int2 e1 = ep[(size_t)(j + 1) * stride];
        int2 e2 = ep[(size_t)(j + 2) * stride];
        int2 e3 = ep[(size_t)(j + 3) * stride];
        f16x8 a0 = *(const f16x8*)(Hc + (size_t)e0.x * 32 + q8);
        f16x8 a1 = *(const f16x8*)(Hc + (size_t)e1.x * 32 + q8);
        f16x8 a2 = *(const f16x8*)(Hc + (size_t)e2.x * 32 + q8);
        f16x8 a3 = *(const f16x8*)(Hc + (size_t)e3.x * 32 + q8);
        float w0 = __int_as_float(e0.y);
        float w1 = __int_as_float(e1.y);
        float w2 = __int_as_float(e2.y);
        float w3 = __int_as_float(e3.y);
        #pragma unroll
        for (int i = 0; i < 8; ++i) {
            acc[i] = fmaf((float)a0[i], w0, acc[i]);
            acc[i] = fmaf((float)a1[i], w1, acc[i]);
            acc[i] = fmaf((float)a2[i], w2, acc[i]);
            acc[i] = fmaf((float)a3[i], w3, acc[i]);
        }
    }
    for (; j < deg; ++j) {
        int2 e0 = ep[(size_t)j * stride];
        f16x8 a0 = *(const f16x8*)(Hc + (size_t)e0.x * 32 + q8);
        float w0 = __int_as_float(e0.y);
        #pragma unroll
        for (int i = 0; i < 8; ++i) acc[i] = fmaf((float)a0[i], w0, acc[i]);
    }

    f16x8 o;
    #pragma unroll
    for (int i = 0; i < 8; ++i) o[i] = (_Float16)acc[i];
    u32x4 uv = *(u32x4*)&o;
    __builtin_nontemporal_store(uv, (u32x4*)(A + (size_t)node * K + chunk * 32 + q8));
}

// ---------------- fused mean-pool + MLP head (one block per graph) ----------------
__global__ __launch_bounds__(128) void k_poolmlp(const _Float16* __restrict__ X16,
                                                 const int* __restrict__ gstart,
                                                 const int* __restrict__ gend,
                                                 const float* __restrict__ W1,
                                                 const float* __restrict__ b1,
                                                 const float* __restrict__ W2,
                                                 const float* __restrict__ b2,
                                                 float* __restrict__ out) {
    __shared__ float prow[HID];
    __shared__ float hred[2];
    int g = blockIdx.x;
    int s = gstart[g], e = gend[g];
    int j = threadIdx.x; // 0..127, channels j and j+128
    const _Float16* p0 = X16 + (size_t)(j >> 5) * (N_NODES * 32) + (j & 31);
    const _Float16* p1 = X16 + (size_t)((j >> 5) + 4) * (N_NODES * 32) + (j & 31);
    float a0 = 0.f, a1 = 0.f;
    for (int n = s; n < e; ++n) {
        a0 += (float)p0[(size_t)n * 32];
        a1 += (float)p1[(size_t)n * 32];
    }
    float inv = 1.0f / fmaxf((float)(e - s), 1.0f);
    prow[j] = a0 * inv;
    prow[j + 128] = a1 * inv;
    __syncthreads();
    float acc = 0.f;
    #pragma unroll 8
    for (int k = 0; k < HID; ++k) acc += prow[k] * W1[k * 128 + j];
    float h = fmaxf(acc + b1[j], 0.f);
    float p = h * W2[j];
    #pragma unroll
    for (int off = 32; off > 0; off >>= 1) p += __shfl_down(p, off, 64);
    if ((j & 63) == 0) hred[j >> 6] = p;
    __syncthreads();
    if (j == 0) out[g] = hred[0] + hred[1] + b2[0];
}

extern "C" void kernel_launch(void* const* d_in, const int* in_sizes, int n_in,
                              void* d_out, int out_size, void* d_ws, size_t ws_size,
                              hipStream_t stream) {
    const float* x      = (const float*)d_in[0];
    const int*   ei     = (const int*)d_in[1];
    const int*   batch  = (const int*)d_in[2];
    const float* convW0 = (const float*)d_in[3];
    const float* convWs = (const float*)d_in[4];
    const float* convB  = (const float*)d_in[5];
    const float* gamma  = (const float*)d_in[6];
    const float* beta   = (const float*)d_in[7];
    const float* mean   = (const float*)d_in[8];
    const float* var    = (const float*)d_in[9];
    const float* lin1W  = (const float*)d_in[10];
    const float* lin1b  = (const float*)d_in[11];
    const float* lin2W  = (const float*)d_in[12];
    const float* lin2b  = (const float*)d_in[13];
    float* out = (float*)d_out;

    const int* src = ei;
    const int* dst = ei + N_EDGES;

    const int WTOT = 128 * 256 + 3 * 256 * 256; // 229376

    char* wsb = (char*)d_ws;
    _Float16* x16a = (_Float16*)wsb;                     // N*HID fp16 (ping)
    _Float16* x16b = x16a + (size_t)N_NODES * HID;       // N*HID fp16 (pong)
    _Float16* Ab   = x16b + (size_t)N_NODES * HID;       // N*HID fp16 (GEMM A operand)
    _Float16* Wh16 = Ab + (size_t)N_NODES * HID;         // WTOT fp16
    _Float16* Wl16 = Wh16 + WTOT;                        // WTOT fp16
    float* dinv    = (float*)(Wl16 + WTOT);              // N
    float* selfn   = dinv + N_NODES;                     // N
    float* bnscale = selfn + N_NODES;                    // 4*HID
    float* bnshift = bnscale + N_LAYERS * HID;           // 4*HID
    // contiguous zero-init region: degi | bins | gstart | gend
    int*   degi    = (int*)(bnshift + N_LAYERS * HID);   // N
    int*   bins    = degi + N_NODES;                     // NBIN
    int*   gstart  = bins + NBIN;                        // G
    int*   gend    = gstart + N_GRAPHS;                  // G
    int*   binstart= gend + N_GRAPHS;                    // NBIN
    int*   bincur  = binstart + NBIN;                    // NBIN
    int*   edgebase= bincur + NBIN;                      // NBIN
    int*   cursor  = edgebase + NBIN;                    // N
    int*   perm    = cursor + N_NODES;                   // N
    int*   invperm = perm + N_NODES;                     // N
    int2*  meta    = (int2*)(invperm + N_NODES);         // N int2
    int2*  edata   = meta + N_NODES;                     // E int2

    hipMemsetAsync(degi, 0, (size_t)(N_NODES + NBIN + 2 * N_GRAPHS) * 4, stream);

    // CSR build + norms + degree sort (all parallel; closed-form offsets)
    k_deg<<<(N_EDGES + 255) / 256, 256, 0, stream>>>(dst, degi, N_EDGES);
    k_nodeprep<<<(N_NODES + 255) / 256, 256, 0, stream>>>(degi, dinv, selfn, bins, N_NODES);
    k_binscan<<<1, 64, 0, stream>>>(bins, binstart, bincur, edgebase);
    k_assign<<<(N_NODES + 255) / 256, 256, 0, stream>>>(degi, binstart, edgebase, bins, bincur,
                                                        perm, invperm, meta, cursor, N_NODES);
    k_fill<<<(N_EDGES + 255) / 256, 256, 0, stream>>>(src, dst, dinv, invperm, meta, cursor,
                                                      edata, N_EDGES);
    k_bounds<<<(N_NODES + 255) / 256, 256, 0, stream>>>(batch, gstart, gend, N_NODES);

    // fused prep: bn affine | weight split (prescaled) | x -> fp16 chunk-major
    const int PREP_TOT = N_LAYERS * HID + WTOT + N_NODES * IN_DIM / 4;
    k_prep<<<(PREP_TOT + 255) / 256, 256, 0, stream>>>(gamma, beta, mean, var, convB,
                                                       convW0, convWs, x,
                                                       bnscale, bnshift, Wh16, Wl16, x16a);

    // layers: gather (Âx, fp16) -> fp16 2-term GEMM (+BN+ReLU epilogue, fp16 out)
    dim3 gg((N_NODES + 127) / 128, 2);
    _Float16* cur = x16a;
    for (int l = 0; l < N_LAYERS; ++l) {
        int K = (l == 0) ? IN_DIM : HID;
        int nchunk = K / 32;
        int cshift = (l == 0) ? 2 : 3;
        size_t woff = (l == 0) ? 0 : (size_t)(32768 + (l - 1) * 65536);
        k_gather<<<nchunk * GNB, 256, 0, stream>>>(cur, meta, edata, perm, selfn,
                                                   Ab, K, cshift);
        _Float16* nxt = (cur == x16a) ? x16b : x16a;
        k_gemm<<<gg, 256, 0, stream>>>(Ab, Wh16 + woff, Wl16 + woff,
                                       bnscale + l * HID, bnshift + l * HID, nxt, K);
        cur = nxt;
    }

    k_poolmlp<<<N_GRAPHS, 128, 0, stream>>>(cur, gstart, gend, lin1W, lin1b, lin2W, lin2b, out);
}

// Round 20
// 502.385 us; speedup vs baseline: 1.6115x; 1.0121x over previous
//
#include <hip/hip_runtime.h>

#define N_NODES 50000
#define N_EDGES 800000
#define N_GRAPHS 2048
#define IN_DIM 128
#define HID 256
#define N_LAYERS 4
#define BN_EPS 1e-5f
#define NBIN 128
#define WSCALE 64.0f

typedef unsigned short ushort_t;
typedef float f32x4 __attribute__((ext_vector_type(4)));
typedef unsigned int u32x4 __attribute__((ext_vector_type(4)));
typedef _Float16 f16x8 __attribute__((ext_vector_type(8)));
typedef _Float16 f16x4 __attribute__((ext_vector_type(4)));

// ---- async global->LDS, 16B per lane ----
__device__ __forceinline__ void gl_lds16(const ushort_t* g, ushort_t* l) {
    __builtin_amdgcn_global_load_lds(
        (const __attribute__((address_space(1))) void*)g,
        (__attribute__((address_space(3))) void*)l, 16, 0, 0);
}

// ---------------- degree count ----------------
__global__ void k_deg(const int* __restrict__ dst, int* __restrict__ degi, int E) {
    int e = blockIdx.x * blockDim.x + threadIdx.x;
    if (e < E) atomicAdd(&degi[dst[e]], 1);
}

// ---------------- node norms + degree histogram (fused, hierarchical) ----------------
__global__ __launch_bounds__(256) void k_nodeprep(const int* __restrict__ degi,
                                                  float* __restrict__ dinv,
                                                  float* __restrict__ selfn,
                                                  int* __restrict__ bins, int N) {
    __shared__ int lbin[NBIN];
    int t = threadIdx.x;
    if (t < NBIN) lbin[t] = 0;
    __syncthreads();
    int n = blockIdx.x * 256 + t;
    if (n < N) {
        int dg = degi[n];
        float d = 1.0f + (float)dg;
        dinv[n] = 1.0f / sqrtf(d);
        selfn[n] = 1.0f / d;
        atomicAdd(&lbin[min(dg, NBIN - 1)], 1);
    }
    __syncthreads();
    if (t < NBIN && lbin[t] > 0) atomicAdd(&bins[t], lbin[t]);
}

// ---------------- bin prefix (tiny serial, 128 iters) ----------------
__global__ void k_binscan(const int* __restrict__ bins, int* __restrict__ binstart,
                          int* __restrict__ bincur, int* __restrict__ edgebase) {
    if (threadIdx.x == 0) {
        int run = 0, erun = 0;
        for (int d = 0; d < NBIN; ++d) {
            binstart[d] = run;
            bincur[d] = run;
            edgebase[d] = erun;
            run += bins[d];
            erun += bins[d] * d;
        }
    }
}

// ---------------- parallel slot assignment, hierarchical; emits per-slot meta ----------------
__global__ __launch_bounds__(256) void k_assign(const int* __restrict__ degi,
                                                const int* __restrict__ binstart,
                                                const int* __restrict__ edgebase,
                                                const int* __restrict__ bins,
                                                int* __restrict__ bincur,
                                                int* __restrict__ perm, int* __restrict__ invperm,
                                                int2* __restrict__ meta, int* __restrict__ cursor,
                                                int N) {
    __shared__ int lbin[NBIN];
    __shared__ int lbase[NBIN];
    int t = threadIdx.x;
    if (t < NBIN) lbin[t] = 0;
    __syncthreads();
    int n = blockIdx.x * 256 + t;
    int d = 0, lrank = 0;
    if (n < N) {
        d = min(degi[n], NBIN - 1);
        lrank = atomicAdd(&lbin[d], 1);
    }
    __syncthreads();
    if (t < NBIN && lbin[t] > 0) lbase[t] = atomicAdd(&bincur[t], lbin[t]);
    __syncthreads();
    if (n < N) {
        int slot = lbase[d] + lrank;
        perm[slot] = n;
        invperm[n] = slot;
        int2 m;
        m.x = edgebase[d] + (slot - binstart[d]);
        m.y = bins[d] | (d << 20);
        meta[slot] = m;
        cursor[slot] = 0;
    }
}

// ---------------- CSR fill into bin-interleaved layout ----------------
__global__ void k_fill(const int* __restrict__ src, const int* __restrict__ dst,
                       const float* __restrict__ dinv, const int* __restrict__ invperm,
                       const int2* __restrict__ meta, int* __restrict__ cursor,
                       int2* __restrict__ edata, int E) {
    int e = blockIdx.x * blockDim.x + threadIdx.x;
    if (e >= E) return;
    int s = src[e], d = dst[e];
    int slot = invperm[d];
    int2 m = meta[slot];
    int j = atomicAdd(&cursor[slot], 1);
    int pos = m.x + j * (m.y & 0xFFFFF);
    int2 v;
    v.x = s;
    v.y = __float_as_int(dinv[s] * dinv[d]);
    edata[pos] = v;
}

// ---------------- graph boundaries from sorted batch ----------------
__global__ void k_bounds(const int* __restrict__ batch, int* __restrict__ gstart,
                         int* __restrict__ gend, int N) {
    int n = blockIdx.x * blockDim.x + threadIdx.x;
    if (n >= N) return;
    int g = batch[n];
    if (n == 0 || batch[n - 1] != g) gstart[g] = n;
    if (n == N - 1 || batch[n + 1] != g) gend[g] = n + 1;
}

// ---------------- fused prep: bnprep | splitw | tochunk (range-dispatched) ----------------
__global__ __launch_bounds__(256) void k_prep(const float* __restrict__ gamma,
                                              const float* __restrict__ beta,
                                              const float* __restrict__ mean,
                                              const float* __restrict__ var,
                                              const float* __restrict__ bias,
                                              const float* __restrict__ W0,
                                              const float* __restrict__ Ws,
                                              const float* __restrict__ x,
                                              float* __restrict__ scale,
                                              float* __restrict__ shift,
                                              _Float16* __restrict__ Wh,
                                              _Float16* __restrict__ Wl,
                                              _Float16* __restrict__ X16) {
    int id = blockIdx.x * 256 + threadIdx.x;
    if (id < N_LAYERS * HID) {
        float s = gamma[id] * rsqrtf(var[id] + BN_EPS);
        scale[id] = s / WSCALE;
        shift[id] = beta[id] + (bias[id] - mean[id]) * s;
        return;
    }
    id -= N_LAYERS * HID;
    const int WT = 128 * 256 + 3 * 256 * 256;
    if (id < WT) {
        float v;
        if (id < 32768) {
            int n = id >> 7, k = id & 127;
            v = W0[k * 256 + n];
        } else {
            int t = id - 32768;
            int l = t >> 16;
            int r = t & 65535;
            int n = r >> 8, k = r & 255;
            v = Ws[l * 65536 + k * 256 + n];
        }
        v *= WSCALE;
        _Float16 h = (_Float16)v;
        Wh[id] = h;
        Wl[id] = (_Float16)(v - (float)h);
        return;
    }
    id -= WT;
    const int total4 = N_NODES * IN_DIM / 4;
    if (id < total4) {
        float4 v = ((const float4*)x)[id];
        int n = id >> 5;
        int c0 = (id & 31) * 4;
        f16x4 o;
        o.x = (_Float16)v.x; o.y = (_Float16)v.y; o.z = (_Float16)v.z; o.w = (_Float16)v.w;
        *(f16x4*)(X16 + (size_t)(c0 >> 5) * (N_NODES * 32) + (size_t)n * 32 + (c0 & 31)) = o;
    }
}

// ---------------- MFMA fp16 2-term GEMM + fused BN/ReLU epilogue (fp16 out) ----------------
// A fp16 node-major [N][K]; W fp16 hi/lo node-major [256][K], prescaled x64
// (1/64 folded into bnscale). Output fp16 chunk-major [8][N][32].
// Staging: 24 tile-groups (A x8 | Wh x8 | Wl x8) dealt 6 per wave (all 4 waves).
__global__ __launch_bounds__(256) void k_gemm(const _Float16* __restrict__ A,
                                              const _Float16* __restrict__ Wh,
                                              const _Float16* __restrict__ Wl,
                                              const float* __restrict__ bnscale,
                                              const float* __restrict__ bnshift,
                                              _Float16* __restrict__ X16, int K) {
    __shared__ _Float16 sm[3 * 128 * 32]; // 24 KB: A | Wh | Wl tiles
    _Float16* tA  = sm;
    _Float16* tWh = sm + 4096;
    _Float16* tWl = sm + 8192;

    int tid = threadIdx.x;
    int lane = tid & 63;
    int w = tid >> 6;
    int wrow = w & 1, wcol = w >> 1;
    int row0 = blockIdx.x * 128;
    int col0 = blockIdx.y * 128;

    int srow = lane >> 2;
    int sch = lane & 3;

    f32x4 acc[4][4] = {};
    int m = lane & 15, q = lane >> 4;

    for (int k0 = 0; k0 < K; k0 += 32) {
        #pragma unroll
        for (int ii = 0; ii < 6; ++ii) {
            int G = w * 6 + ii;       // 0..23
            int mat = G >> 3;         // 0=A, 1=Wh, 2=Wl
            int grp = G & 7;
            const _Float16* gs = (mat == 0) ? A : (mat == 1) ? Wh : Wl;
            _Float16* ld = sm + mat * 4096;
            int rb = (mat == 0) ? row0 : col0;
            int rl = (mat == 0) ? N_NODES : (col0 + 128);
            int r = grp * 16 + srow;
            int grow = rb + r;
            int gch = sch ^ (r & 3);
            if (grow < rl)
                gl_lds16((const ushort_t*)(gs + (size_t)grow * K + k0 + gch * 8),
                         (ushort_t*)(ld + grp * 512));
        }
        __syncthreads();

        f16x8 af[4], whf[4], wlf[4];
        #pragma unroll
        for (int r = 0; r < 4; ++r) {
            int rr = wrow * 64 + r * 16 + m;
            int off = rr * 32 + ((q ^ (rr & 3)) << 3);
            af[r] = *(const f16x8*)(tA + off);
        }
        #pragma unroll
        for (int c = 0; c < 4; ++c) {
            int nn = wcol * 64 + c * 16 + m;
            int off = nn * 32 + ((q ^ (nn & 3)) << 3);
            whf[c] = *(const f16x8*)(tWh + off);
            wlf[c] = *(const f16x8*)(tWl + off);
        }
        #pragma unroll
        for (int r = 0; r < 4; ++r)
            #pragma unroll
            for (int c = 0; c < 4; ++c) {
                acc[r][c] = __builtin_amdgcn_mfma_f32_16x16x32_f16(af[r], whf[c], acc[r][c], 0, 0, 0);
                acc[r][c] = __builtin_amdgcn_mfma_f32_16x16x32_f16(af[r], wlf[c], acc[r][c], 0, 0, 0);
            }
        __syncthreads();
    }

    #pragma unroll
    for (int r = 0; r < 4; ++r) {
        int mrow = row0 + wrow * 64 + r * 16 + (lane >> 4) * 4;
        #pragma unroll
        for (int c = 0; c < 4; ++c) {
            int n = col0 + wcol * 64 + c * 16 + (lane & 15);
            float sc = bnscale[n];
            float sh = bnshift[n];
            f32x4 v = acc[r][c];
            _Float16* base = X16 + (size_t)(n >> 5) * (N_NODES * 32) + (n & 31);
            #pragma unroll
            for (int g = 0; g < 4; ++g)
                if (mrow + g < N_NODES)
                    base[(size_t)(mrow + g) * 32] =
                        (_Float16)fmaxf(fmaf(v[g], sc, sh), 0.f);
        }
    }
}

// ---------------- chunked gather on fp16 X: Âx -> fp16 A node-major ----------------
#define GNB 782  // ceil(50000/64) slot-blocks per chunk

__global__ __launch_bounds__(256) void k_gather(const _Float16* __restrict__ Xc,
                                                const int2* __restrict__ meta,
                                                const int2* __restrict__ edata,
                                                const int* __restrict__ perm,
                                                const float* __restrict__ selfn,
                                                _Float16* __restrict__ A,
                                                int K, int cshift) {
    int bid = blockIdx.x;
    int chunk = bid & ((1 << cshift) - 1);
    int nb = bid >> cshift;
    const _Float16* Hc = Xc + (size_t)chunk * (N_NODES * 32);
    int slot = nb * 64 + (threadIdx.x >> 2);
    if (slot >= N_NODES) return;
    int node = perm[slot];
    int2 m = meta[slot];
    int q8 = (threadIdx.x & 3) * 8;

    int stride = m.y & 0xFFFFF;
    int deg = m.y >> 20;
    const int2* ep = edata + m.x;
    float sn = selfn[node];

    float acc[8];
    {
        f16x8 hv = *(const f16x8*)(Hc + (size_t)node * 32 + q8);
        #pragma unroll
        for (int i = 0; i < 8; ++i) acc[i] = (float)hv[i] * sn;
    }
    int j = 0;
    for (; j + 3 < deg; j += 4) {
        int2 e0 = ep[(size_t)(j + 0) * stride];
        int2 e1 = ep[(size_t)(j + 1) * stride];
        int2 e2 = ep[(size_t)(j + 2) * stride];
        int2 e3 = ep[(size_t)(j + 3) * stride];
        f16x8 a0 = *(const f16x8*)(Hc + (size_t)e0.x * 32 + q8);
        f16x8 a1 = *(const f16x8*)(Hc + (size_t)e1.x * 32 + q8);
        f16x8 a2 = *(const f16x8*)(Hc + (size_t)e2.x * 32 + q8);
        f16x8 a3 = *(const f16x8*)(Hc + (size_t)e3.x * 32 + q8);
        float w0 = __int_as_float(e0.y);
        float w1 = __int_as_float(e1.y);
        float w2 = __int_as_float(e2.y);
        float w3 = __int_as_float(e3.y);
        #pragma unroll
        for (int i = 0; i < 8; ++i) {
            acc[i] = fmaf((float)a0[i], w0, acc[i]);
            acc[i] = fmaf((float)a1[i], w1, acc[i]);
            acc[i] = fmaf((float)a2[i], w2, acc[i]);
            acc[i] = fmaf((float)a3[i], w3, acc[i]);
        }
    }
    for (; j < deg; ++j) {
        int2 e0 = ep[(size_t)j * stride];
        f16x8 a0 = *(const f16x8*)(Hc + (size_t)e0.x * 32 + q8);
        float w0 = __int_as_float(e0.y);
        #pragma unroll
        for (int i = 0; i < 8; ++i) acc[i] = fmaf((float)a0[i], w0, acc[i]);
    }

    f16x8 o;
    #pragma unroll
    for (int i = 0; i < 8; ++i) o[i] = (_Float16)acc[i];
    u32x4 uv = *(u32x4*)&o;
    __builtin_nontemporal_store(uv, (u32x4*)(A + (size_t)node * K + chunk * 32 + q8));
}

// ---------------- fused mean-pool + MLP head (one block per graph) ----------------
__global__ __launch_bounds__(128) void k_poolmlp(const _Float16* __restrict__ X16,
                                                 const int* __restrict__ gstart,
                                                 const int* __restrict__ gend,
                                                 const float* __restrict__ W1,
                                                 const float* __restrict__ b1,
                                                 const float* __restrict__ W2,
                                                 const float* __restrict__ b2,
                                                 float* __restrict__ out) {
    __shared__ float prow[HID];
    __shared__ float hred[2];
    int g = blockIdx.x;
    int s = gstart[g], e = gend[g];
    int j = threadIdx.x; // 0..127, channels j and j+128
    const _Float16* p0 = X16 + (size_t)(j >> 5) * (N_NODES * 32) + (j & 31);
    const _Float16* p1 = X16 + (size_t)((j >> 5) + 4) * (N_NODES * 32) + (j & 31);
    float a0 = 0.f, a1 = 0.f;
    for (int n = s; n < e; ++n) {
        a0 += (float)p0[(size_t)n * 32];
        a1 += (float)p1[(size_t)n * 32];
    }
    float inv = 1.0f / fmaxf((float)(e - s), 1.0f);
    prow[j] = a0 * inv;
    prow[j + 128] = a1 * inv;
    __syncthreads();
    float acc = 0.f;
    #pragma unroll 8
    for (int k = 0; k < HID; ++k) acc += prow[k] * W1[k * 128 + j];
    float h = fmaxf(acc + b1[j], 0.f);
    float p = h * W2[j];
    #pragma unroll
    for (int off = 32; off > 0; off >>= 1) p += __shfl_down(p, off, 64);
    if ((j & 63) == 0) hred[j >> 6] = p;
    __syncthreads();
    if (j == 0) out[g] = hred[0] + hred[1] + b2[0];
}

extern "C" void kernel_launch(void* const* d_in, const int* in_sizes, int n_in,
                              void* d_out, int out_size, void* d_ws, size_t ws_size,
                              hipStream_t stream) {
    const float* x      = (const float*)d_in[0];
    const int*   ei     = (const int*)d_in[1];
    const int*   batch  = (const int*)d_in[2];
    const float* convW0 = (const float*)d_in[3];
    const float* convWs = (const float*)d_in[4];
    const float* convB  = (const float*)d_in[5];
    const float* gamma  = (const float*)d_in[6];
    const float* beta   = (const float*)d_in[7];
    const float* mean   = (const float*)d_in[8];
    const float* var    = (const float*)d_in[9];
    const float* lin1W  = (const float*)d_in[10];
    const float* lin1b  = (const float*)d_in[11];
    const float* lin2W  = (const float*)d_in[12];
    const float* lin2b  = (const float*)d_in[13];
    float* out = (float*)d_out;

    const int* src = ei;
    const int* dst = ei + N_EDGES;

    const int WTOT = 128 * 256 + 3 * 256 * 256; // 229376

    char* wsb = (char*)d_ws;
    _Float16* x16a = (_Float16*)wsb;                     // N*HID fp16 (ping)
    _Float16* x16b = x16a + (size_t)N_NODES * HID;       // N*HID fp16 (pong)
    _Float16* Ab   = x16b + (size_t)N_NODES * HID;       // N*HID fp16 (GEMM A operand)
    _Float16* Wh16 = Ab + (size_t)N_NODES * HID;         // WTOT fp16
    _Float16* Wl16 = Wh16 + WTOT;                        // WTOT fp16
    float* dinv    = (float*)(Wl16 + WTOT);              // N
    float* selfn   = dinv + N_NODES;                     // N
    float* bnscale = selfn + N_NODES;                    // 4*HID
    float* bnshift = bnscale + N_LAYERS * HID;           // 4*HID
    // contiguous zero-init region: degi | bins | gstart | gend
    int*   degi    = (int*)(bnshift + N_LAYERS * HID);   // N
    int*   bins    = degi + N_NODES;                     // NBIN
    int*   gstart  = bins + NBIN;                        // G
    int*   gend    = gstart + N_GRAPHS;                  // G
    int*   binstart= gend + N_GRAPHS;                    // NBIN
    int*   bincur  = binstart + NBIN;                    // NBIN
    int*   edgebase= bincur + NBIN;                      // NBIN
    int*   cursor  = edgebase + NBIN;                    // N
    int*   perm    = cursor + N_NODES;                   // N
    int*   invperm = perm + N_NODES;                     // N
    int2*  meta    = (int2*)(invperm + N_NODES);         // N int2
    int2*  edata   = meta + N_NODES;                     // E int2

    hipMemsetAsync(degi, 0, (size_t)(N_NODES + NBIN + 2 * N_GRAPHS) * 4, stream);

    // CSR build + norms + degree sort (all parallel; closed-form offsets)
    k_deg<<<(N_EDGES + 255) / 256, 256, 0, stream>>>(dst, degi, N_EDGES);
    k_nodeprep<<<(N_NODES + 255) / 256, 256, 0, stream>>>(degi, dinv, selfn, bins, N_NODES);
    k_binscan<<<1, 64, 0, stream>>>(bins, binstart, bincur, edgebase);
    k_assign<<<(N_NODES + 255) / 256, 256, 0, stream>>>(degi, binstart, edgebase, bins, bincur,
                                                        perm, invperm, meta, cursor, N_NODES);
    k_fill<<<(N_EDGES + 255) / 256, 256, 0, stream>>>(src, dst, dinv, invperm, meta, cursor,
                                                      edata, N_EDGES);
    k_bounds<<<(N_NODES + 255) / 256, 256, 0, stream>>>(batch, gstart, gend, N_NODES);

    // fused prep: bn affine | weight split (prescaled) | x -> fp16 chunk-major
    const int PREP_TOT = N_LAYERS * HID + WTOT + N_NODES * IN_DIM / 4;
    k_prep<<<(PREP_TOT + 255) / 256, 256, 0, stream>>>(gamma, beta, mean, var, convB,
                                                       convW0, convWs, x,
                                                       bnscale, bnshift, Wh16, Wl16, x16a);

    // layers: gather (Âx, fp16) -> fp16 2-term GEMM (+BN+ReLU epilogue, fp16 out)
    dim3 gg((N_NODES + 127) / 128, 2);
    _Float16* cur = x16a;
    for (int l = 0; l < N_LAYERS; ++l) {
        int K = (l == 0) ? IN_DIM : HID;
        int nchunk = K / 32;
        int cshift = (l == 0) ? 2 : 3;
        size_t woff = (l == 0) ? 0 : (size_t)(32768 + (l - 1) * 65536);
        k_gather<<<nchunk * GNB, 256, 0, stream>>>(cur, meta, edata, perm, selfn,
                                                   Ab, K, cshift);
        _Float16* nxt = (cur == x16a) ? x16b : x16a;
        k_gemm<<<gg, 256, 0, stream>>>(Ab, Wh16 + woff, Wl16 + woff,
                                       bnscale + l * HID, bnshift + l * HID, nxt, K);
        cur = nxt;
    }

    k_poolmlp<<<N_GRAPHS, 128, 0, stream>>>(cur, gstart, gend, lin1W, lin1b, lin2W, lin2b, out);
}